// Round 1
// baseline (1435.993 us; speedup 1.0000x reference)
//
#include <hip/hip_runtime.h>
#include <hip/hip_bf16.h>
#include <math.h>

// Problem constants: N=4096, D=512, H=8, DH=64, K_SEL=10, C=4
#define DEV __device__ __forceinline__

typedef __attribute__((ext_vector_type(4))) float  f32x4;
typedef __attribute__((ext_vector_type(8))) short  bf8_t;   // 8 x bf16 (4 VGPRs)
typedef unsigned int   u32;
typedef unsigned short u16;

DEV u16 f2bf(float f){
  u32 u = __builtin_bit_cast(u32, f);
  u32 r = (u + 0x7fffu + ((u >> 16) & 1u)) >> 16;   // RNE
  return (u16)r;
}
DEV float bf2f(u16 h){ u32 u = ((u32)h) << 16; return __builtin_bit_cast(float, u); }
// XOR-swizzle on 16B chunks with row&7 (bank-conflict fix for ds_read_b128)
DEV u32 swzB(u32 r, u32 b, u32 rowBytes){ return r*rowBytes + (b ^ ((r & 7u) << 4)); }

// ---------------- elementwise split kernels ----------------
__global__ void k_split_act(const float* __restrict__ x, u16* __restrict__ hi,
                            u16* __restrict__ lo, int n){
  int i = blockIdx.x*256 + threadIdx.x;
  if (i < n){ float v = x[i]; u16 h = f2bf(v); hi[i]=h; lo[i]=f2bf(v - bf2f(h)); }
}

// W [512][512] fp32 -> transposed split Wt[col][k] bf16 hi/lo
__global__ void k_split_wT(const float* __restrict__ w, u16* __restrict__ thi,
                           u16* __restrict__ tlo){
  int i = blockIdx.x*256 + threadIdx.x;       // over 512*512
  int k = i >> 9, c = i & 511;
  float v = w[i];
  u16 h = f2bf(v);
  thi[c*512 + k] = h;
  tlo[c*512 + k] = f2bf(v - bf2f(h));
}

// ---------------- LayerNorm -> split bf16 ----------------
__global__ __launch_bounds__(256) void k_ln_split(
    const float* __restrict__ x, const float* __restrict__ g, const float* __restrict__ b,
    u16* __restrict__ hhi, u16* __restrict__ hlo)
{
  const int w = threadIdx.x >> 6, lane = threadIdx.x & 63;
  const int row = blockIdx.x*4 + w;
  const float* xr = x + row*512;
  float v[8];
  f32x4 a  = *(const f32x4*)(xr + lane*8);
  f32x4 a2 = *(const f32x4*)(xr + lane*8 + 4);
  v[0]=a.x; v[1]=a.y; v[2]=a.z; v[3]=a.w; v[4]=a2.x; v[5]=a2.y; v[6]=a2.z; v[7]=a2.w;
  float s = v[0]+v[1]+v[2]+v[3]+v[4]+v[5]+v[6]+v[7];
  #pragma unroll
  for (int m=1;m<64;m<<=1) s += __shfl_xor(s, m);
  const float mean = s * (1.0f/512.0f);
  float q = 0.f;
  #pragma unroll
  for (int i=0;i<8;++i){ const float d = v[i]-mean; q += d*d; }
  #pragma unroll
  for (int m=1;m<64;m<<=1) q += __shfl_xor(q, m);
  const float rstd = 1.0f / sqrtf(q*(1.0f/512.0f) + 1e-5f);
  #pragma unroll
  for (int i=0;i<8;++i){
    const int c = lane*8 + i;
    const float y = (v[i]-mean)*rstd*g[c] + b[c];
    const u16 hv = f2bf(y);
    hhi[row*512 + c] = hv;
    hlo[row*512 + c] = f2bf(y - bf2f(hv));
  }
}

// ---------------- generic K=512, N=512 GEMM (M=4096), split-bf16 capable ----------------
enum { EPI_GELU=0, EPI_SPLIT=1, EPI_VT=2, EPI_RES=3 };

template<int TERMS, int EPI>
__global__ __launch_bounds__(256) void k_gemm512(
    const u16* __restrict__ Ahi, const u16* __restrict__ Alo,
    const u16* __restrict__ Bthi, const u16* __restrict__ Btlo,  // transposed weights [col][k]
    const float* __restrict__ bias, const float* __restrict__ resid,
    float* __restrict__ outF, u16* __restrict__ outA, u16* __restrict__ outB)
{
  __shared__ __align__(16) char ls[32768];   // ahi@0 alo@8K bhi@16K blo@24K  ([64][64] bf16 each)
  const int t = threadIdx.x;
  const int w = t >> 6, lane = t & 63;
  const int n0 = blockIdx.x * 64;
  const int c0 = blockIdx.y * 64;
  const int wr = w >> 1, wc = w & 1;
  const int lr = lane & 15, lg = lane >> 4;

  f32x4 acc[2][2];
  #pragma unroll
  for (int i=0;i<2;++i)
    #pragma unroll
    for (int j=0;j<2;++j) acc[i][j] = f32x4{0.f,0.f,0.f,0.f};

  for (int bk = 0; bk < 8; ++bk) {
    const int kb = bk * 64;
    __syncthreads();
    #pragma unroll 2
    for (int i = t; i < 512; i += 256) {
      const int r = i >> 3, c = i & 7;
      const u32 dst = swzB(r, c*16, 128);
      const int ga = (n0 + r)*512 + kb + c*8;
      const int gb = (c0 + r)*512 + kb + c*8;
      *(uint4*)(ls + dst)         = *(const uint4*)(Ahi  + ga);
      *(uint4*)(ls + 16384 + dst) = *(const uint4*)(Bthi + gb);
      if constexpr (TERMS >= 3) {
        *(uint4*)(ls + 8192  + dst) = *(const uint4*)(Alo  + ga);
        *(uint4*)(ls + 24576 + dst) = *(const uint4*)(Btlo + gb);
      }
    }
    __syncthreads();
    #pragma unroll
    for (int ks = 0; ks < 2; ++ks) {
      const u32 co = ks*64 + lg*16;
      bf8_t ah[2], bh[2], al[2], bl[2];
      #pragma unroll
      for (int i=0;i<2;++i) {
        ah[i] = *(const bf8_t*)(ls +         swzB(wr*32 + i*16 + lr, co, 128));
        bh[i] = *(const bf8_t*)(ls + 16384 + swzB(wc*32 + i*16 + lr, co, 128));
        if constexpr (TERMS >= 3) {
          al[i] = *(const bf8_t*)(ls + 8192  + swzB(wr*32 + i*16 + lr, co, 128));
          bl[i] = *(const bf8_t*)(ls + 24576 + swzB(wc*32 + i*16 + lr, co, 128));
        }
      }
      #pragma unroll
      for (int i=0;i<2;++i)
        #pragma unroll
        for (int j=0;j<2;++j) {
          acc[i][j] = __builtin_amdgcn_mfma_f32_16x16x32_bf16(ah[i], bh[j], acc[i][j], 0,0,0);
          if constexpr (TERMS >= 3) {
            acc[i][j] = __builtin_amdgcn_mfma_f32_16x16x32_bf16(ah[i], bl[j], acc[i][j], 0,0,0);
            acc[i][j] = __builtin_amdgcn_mfma_f32_16x16x32_bf16(al[i], bh[j], acc[i][j], 0,0,0);
          }
        }
    }
  }
  #pragma unroll
  for (int i=0;i<2;++i)
    #pragma unroll
    for (int j=0;j<2;++j) {
      const int col = c0 + wc*32 + j*16 + lr;
      #pragma unroll
      for (int r=0;r<4;++r) {
        const int row = n0 + wr*32 + i*16 + lg*4 + r;
        float v = acc[i][j][r];
        if constexpr (EPI == EPI_GELU) {
          v += bias[col];
          outF[row*512 + col] = 0.5f * v * (1.0f + erff(v * 0.70710678118654752f));
        } else if constexpr (EPI == EPI_SPLIT) {
          const u16 hv = f2bf(v);
          outA[row*512 + col] = hv;
          outB[row*512 + col] = f2bf(v - bf2f(hv));
        } else if constexpr (EPI == EPI_VT) {
          outA[col*4096 + row] = f2bf(v);                 // V transposed [d][n]
        } else {
          outF[row*512 + col] = v + resid[row*512 + col]; // residual add
        }
      }
    }
}

// ---------------- fused attention: per (head, 64 q-rows) block ----------------
// pass1: row sum of exp(s) with hi*hi scores; pass2: split scores -> p, colsum partials, P@V
__global__ __launch_bounds__(256) void k_attn(
    const u16* __restrict__ qhi, const u16* __restrict__ qlo,
    const u16* __restrict__ khi, const u16* __restrict__ klo,
    const u16* __restrict__ vt,  u16* __restrict__ ov, float* __restrict__ Apart)
{
  // LDS: 0:qhi[64][64] 8K:qlo 16K:khi[128][64] (P[64][128] alias) 32K:klo 48K... 49152:vt[64][128] (red/rinv alias in pass1)
  __shared__ __align__(16) char ls[65536];
  const int t = threadIdx.x, w = t >> 6, lane = t & 63;
  const int lr = lane & 15, lg = lane >> 4;
  const int nb = blockIdx.x, h = blockIdx.y;
  const int n0 = nb * 64, qc0 = h * 64;
  const float cexp = 0.18033688011112042f;   // log2(e)/8  (scores /sqrt(64))

  for (int i = t; i < 1024; i += 256) {      // stage Q hi/lo
    const int buf = i >> 9, rem = i & 511, r = rem >> 3, c = rem & 7;
    const u16* src = (buf ? qlo : qhi) + (n0 + r)*512 + qc0 + c*8;
    *(uint4*)(ls + buf*8192 + swzB(r, c*16, 128)) = *(const uint4*)src;
  }

  // ---- pass 1: l_n ----
  float rs[16];
  #pragma unroll
  for (int i=0;i<16;++i) rs[i] = 0.f;
  for (int mt = 0; mt < 32; ++mt) {
    const int m0 = mt * 128;
    __syncthreads();
    for (int i = t; i < 1024; i += 256) {
      const int r = i >> 3, c = i & 7;
      *(uint4*)(ls + 16384 + swzB(r, c*16, 128)) = *(const uint4*)(khi + (m0 + r)*512 + qc0 + c*8);
    }
    __syncthreads();
    f32x4 sacc[4][2];
    #pragma unroll
    for (int i=0;i<4;++i){ sacc[i][0]=f32x4{0.f,0.f,0.f,0.f}; sacc[i][1]=f32x4{0.f,0.f,0.f,0.f}; }
    #pragma unroll
    for (int ks=0; ks<2; ++ks) {
      const u32 co = ks*64 + lg*16;
      bf8_t aq[4], bk[2];
      #pragma unroll
      for (int i=0;i<4;++i) aq[i] = *(const bf8_t*)(ls + swzB(i*16 + lr, co, 128));
      #pragma unroll
      for (int j=0;j<2;++j) bk[j] = *(const bf8_t*)(ls + 16384 + swzB(w*32 + j*16 + lr, co, 128));
      #pragma unroll
      for (int i=0;i<4;++i)
        #pragma unroll
        for (int j=0;j<2;++j)
          sacc[i][j] = __builtin_amdgcn_mfma_f32_16x16x32_bf16(aq[i], bk[j], sacc[i][j], 0,0,0);
    }
    #pragma unroll
    for (int i=0;i<4;++i)
      #pragma unroll
      for (int j=0;j<2;++j)
        #pragma unroll
        for (int r=0;r<4;++r)
          rs[i*4+r] += exp2f(sacc[i][j][r] * cexp);
  }
  #pragma unroll
  for (int i=0;i<16;++i){
    float v = rs[i];
    v += __shfl_xor(v, 1); v += __shfl_xor(v, 2);
    v += __shfl_xor(v, 4); v += __shfl_xor(v, 8);
    rs[i] = v;
  }
  __syncthreads();
  if (lr == 0) {
    float* red = (float*)(ls + 49152);
    #pragma unroll
    for (int i=0;i<4;++i)
      #pragma unroll
      for (int r=0;r<4;++r)
        red[w*64 + i*16 + lg*4 + r] = rs[i*4+r];
  }
  __syncthreads();
  if (t < 64) {
    const float* red = (const float*)(ls + 49152);
    const float lsum = red[t] + red[64+t] + red[128+t] + red[192+t];
    ((float*)(ls + 49152 + 1024))[t] = 1.0f / lsum;
  }
  __syncthreads();
  float rv[16];
  #pragma unroll
  for (int i=0;i<4;++i)
    #pragma unroll
    for (int r=0;r<4;++r)
      rv[i*4+r] = ((const float*)(ls + 49152 + 1024))[i*16 + lg*4 + r];

  // ---- pass 2 ----
  f32x4 oacc[4];
  #pragma unroll
  for (int i=0;i<4;++i) oacc[i] = f32x4{0.f,0.f,0.f,0.f};
  for (int mt = 0; mt < 32; ++mt) {
    const int m0 = mt * 128;
    __syncthreads();
    for (int i = t; i < 1024; i += 256) {
      const int r = i >> 3, c = i & 7;
      const u32 dst = swzB(r, c*16, 128);
      const int gk = (m0 + r)*512 + qc0 + c*8;
      *(uint4*)(ls + 16384 + dst) = *(const uint4*)(khi + gk);
      *(uint4*)(ls + 32768 + dst) = *(const uint4*)(klo + gk);
    }
    for (int i = t; i < 1024; i += 256) {
      const int r = i >> 4, c = i & 15;
      *(uint4*)(ls + 49152 + swzB(r, c*16, 256)) = *(const uint4*)(vt + (qc0 + r)*4096 + m0 + c*8);
    }
    __syncthreads();
    f32x4 sacc[4][2];
    #pragma unroll
    for (int i=0;i<4;++i){ sacc[i][0]=f32x4{0.f,0.f,0.f,0.f}; sacc[i][1]=f32x4{0.f,0.f,0.f,0.f}; }
    #pragma unroll
    for (int ks = 0; ks < 2; ++ks) {
      const u32 co = ks*64 + lg*16;
      bf8_t aqh[4], aql[4], bkh[2], bkl[2];
      #pragma unroll
      for (int i=0;i<4;++i){
        aqh[i] = *(const bf8_t*)(ls +        swzB(i*16 + lr, co, 128));
        aql[i] = *(const bf8_t*)(ls + 8192 + swzB(i*16 + lr, co, 128));
      }
      #pragma unroll
      for (int j=0;j<2;++j){
        bkh[j] = *(const bf8_t*)(ls + 16384 + swzB(w*32 + j*16 + lr, co, 128));
        bkl[j] = *(const bf8_t*)(ls + 32768 + swzB(w*32 + j*16 + lr, co, 128));
      }
      #pragma unroll
      for (int i=0;i<4;++i)
        #pragma unroll
        for (int j=0;j<2;++j){
          sacc[i][j] = __builtin_amdgcn_mfma_f32_16x16x32_bf16(aqh[i], bkh[j], sacc[i][j], 0,0,0);
          sacc[i][j] = __builtin_amdgcn_mfma_f32_16x16x32_bf16(aqh[i], bkl[j], sacc[i][j], 0,0,0);
          sacc[i][j] = __builtin_amdgcn_mfma_f32_16x16x32_bf16(aql[i], bkh[j], sacc[i][j], 0,0,0);
        }
    }
    __syncthreads();   // all waves done with K tiles; P may overwrite khi region
    float cs[2] = {0.f, 0.f};
    #pragma unroll
    for (int i=0;i<4;++i)
      #pragma unroll
      for (int j=0;j<2;++j)
        #pragma unroll
        for (int r=0;r<4;++r){
          const float e = exp2f(sacc[i][j][r] * cexp);
          const float p = e * rv[i*4+r];
          cs[j] += p;
          const int prow = i*16 + lg*4 + r;
          const int pcol = w*32 + j*16 + lr;
          *(u16*)(ls + 16384 + swzB(prow, pcol*2, 256)) = f2bf(p);
        }
    #pragma unroll
    for (int j=0;j<2;++j){
      float v = cs[j];
      v += __shfl_xor(v, 16); v += __shfl_xor(v, 32);
      cs[j] = v;
    }
    if (lane < 16) {
      const int base = (h*64 + nb)*4096 + m0 + w*32;
      Apart[base + lane]      = cs[0];
      Apart[base + 16 + lane] = cs[1];
    }
    __syncthreads();   // P fully written
    #pragma unroll
    for (int ks2 = 0; ks2 < 4; ++ks2) {
      const u32 co = ks2*64 + lg*16;
      const bf8_t bv = *(const bf8_t*)(ls + 49152 + swzB(w*16 + lr, co, 256));
      #pragma unroll
      for (int i=0;i<4;++i){
        const bf8_t ap = *(const bf8_t*)(ls + 16384 + swzB(i*16 + lr, co, 256));
        oacc[i] = __builtin_amdgcn_mfma_f32_16x16x32_bf16(ap, bv, oacc[i], 0,0,0);
      }
    }
  }
  #pragma unroll
  for (int i=0;i<4;++i)
    #pragma unroll
    for (int r=0;r<4;++r){
      const int row = n0 + i*16 + lg*4 + r;
      const int col = qc0 + w*16 + lr;
      ov[row*512 + col] = f2bf(oacc[i][r]);
    }
}

// ---------------- A reduction (deterministic fp64) + exact stable-argsort top/bottom-K ----------------
__global__ void k_reduceA(const float* __restrict__ Apart, double* __restrict__ A64){
  const int m = blockIdx.x*256 + threadIdx.x;
  double s = 0.0;
  for (int b=0;b<512;++b) s += (double)Apart[b*4096 + m];
  A64[m] = s;
}

__global__ __launch_bounds__(256) void k_select(const double* __restrict__ A64, int* __restrict__ idx){
  __shared__ double Aw[4096];
  __shared__ double bv[256];
  __shared__ int    bi[256];
  const int t = threadIdx.x;
  for (int i=t;i<4096;i+=256) Aw[i] = A64[i];
  __syncthreads();
  for (int k=0;k<10;++k){                         // top-K: max, tie -> smaller index
    double best = -1e300; int bidx = 1<<30;
    for (int i=t;i<4096;i+=256){
      const double v = Aw[i];
      if (v > best){ best = v; bidx = i; }
    }
    bv[t]=best; bi[t]=bidx;
    __syncthreads();
    for (int s2=128;s2>0;s2>>=1){
      if (t < s2){
        const double v = bv[t+s2]; const int ii = bi[t+s2];
        if (v > bv[t] || (v == bv[t] && ii < bi[t])){ bv[t]=v; bi[t]=ii; }
      }
      __syncthreads();
    }
    if (t==0){ idx[k] = bi[0]; Aw[bi[0]] = -1e300; }
    __syncthreads();
  }
  for (int i=t;i<4096;i+=256) Aw[i] = A64[i];
  __syncthreads();
  for (int k=0;k<10;++k){                         // bottom-K from the end: min, tie -> larger index
    double best = 1e300; int bidx = -1;
    for (int i=t;i<4096;i+=256){
      const double v = Aw[i];
      if (v < best || (v == best && i > bidx)){ best = v; bidx = i; }
    }
    bv[t]=best; bi[t]=bidx;
    __syncthreads();
    for (int s2=128;s2>0;s2>>=1){
      if (t < s2){
        const double v = bv[t+s2]; const int ii = bi[t+s2];
        if (v < bv[t] || (v == bv[t] && ii > bi[t])){ bv[t]=v; bi[t]=ii; }
      }
      __syncthreads();
    }
    if (t==0){ idx[19-k] = bi[0]; Aw[bi[0]] = 1e300; }
    __syncthreads();
  }
}

// ---------------- feats = LN(x_res): mean over rows (partials), and selected rows ----------------
__global__ __launch_bounds__(256) void k_slide_part(const float* __restrict__ xres,
                                                    float* __restrict__ spart){
  __shared__ float acc[4][512];
  const int t = threadIdx.x, w = t >> 6, lane = t & 63;
  float la[8];
  #pragma unroll
  for (int i=0;i<8;++i) la[i]=0.f;
  for (int rr = 0; rr < 16; ++rr) {
    const int row = blockIdx.x*64 + w*16 + rr;
    const float* xr = xres + row*512;
    float v[8];
    f32x4 a  = *(const f32x4*)(xr + lane*8);
    f32x4 a2 = *(const f32x4*)(xr + lane*8 + 4);
    v[0]=a.x; v[1]=a.y; v[2]=a.z; v[3]=a.w; v[4]=a2.x; v[5]=a2.y; v[6]=a2.z; v[7]=a2.w;
    float s = v[0]+v[1]+v[2]+v[3]+v[4]+v[5]+v[6]+v[7];
    #pragma unroll
    for (int m=1;m<64;m<<=1) s += __shfl_xor(s, m);
    const float mean = s * (1.0f/512.0f);
    float q = 0.f;
    #pragma unroll
    for (int i=0;i<8;++i){ const float d = v[i]-mean; q += d*d; }
    #pragma unroll
    for (int m=1;m<64;m<<=1) q += __shfl_xor(q, m);
    const float rstd = 1.0f / sqrtf(q*(1.0f/512.0f) + 1e-5f);
    #pragma unroll
    for (int i=0;i<8;++i) la[i] += (v[i]-mean)*rstd;   // g,b applied at reduce (linear)
  }
  #pragma unroll
  for (int i=0;i<8;++i) acc[w][lane*8+i] = la[i];
  __syncthreads();
  for (int c = t; c < 512; c += 256)
    spart[blockIdx.x*512 + c] = acc[0][c]+acc[1][c]+acc[2][c]+acc[3][c];
}

__global__ void k_slide_reduce(const float* __restrict__ spart, const float* __restrict__ g,
                               const float* __restrict__ b, float* __restrict__ tok){
  const int c = blockIdx.x*256 + threadIdx.x;
  float s = 0.f;
  for (int bb=0;bb<64;++bb) s += spart[bb*512 + c];
  tok[c] = g[c]*(s*(1.0f/4096.0f)) + b[c];
}

__global__ void k_atte(const float* __restrict__ xres, const int* __restrict__ idx,
                       const float* __restrict__ g, const float* __restrict__ b,
                       float* __restrict__ atte){
  const int i = blockIdx.x, lane = threadIdx.x;   // 64 threads = 1 wave
  const int row = idx[i];
  const float* xr = xres + row*512;
  float v[8];
  f32x4 a  = *(const f32x4*)(xr + lane*8);
  f32x4 a2 = *(const f32x4*)(xr + lane*8 + 4);
  v[0]=a.x; v[1]=a.y; v[2]=a.z; v[3]=a.w; v[4]=a2.x; v[5]=a2.y; v[6]=a2.z; v[7]=a2.w;
  float s = v[0]+v[1]+v[2]+v[3]+v[4]+v[5]+v[6]+v[7];
  #pragma unroll
  for (int m=1;m<64;m<<=1) s += __shfl_xor(s, m);
  const float mean = s * (1.0f/512.0f);
  float q = 0.f;
  #pragma unroll
  for (int i2=0;i2<8;++i2){ const float d = v[i2]-mean; q += d*d; }
  #pragma unroll
  for (int m=1;m<64;m<<=1) q += __shfl_xor(q, m);
  const float rstd = 1.0f / sqrtf(q*(1.0f/512.0f) + 1e-5f);
  #pragma unroll
  for (int i2=0;i2<8;++i2){
    const int c = lane*8 + i2;
    atte[i*512 + c] = (v[i2]-mean)*rstd*g[c] + b[c];
  }
}

// ---------------- tiny head: logits + contrastive loss ----------------
__global__ __launch_bounds__(256) void k_head(
    const float* __restrict__ tokH, const float* __restrict__ tokI,
    const float* __restrict__ atteH, const float* __restrict__ atteI,
    const float* __restrict__ WheC, const float* __restrict__ bheC,
    const float* __restrict__ WihcC, const float* __restrict__ bihcC,
    const float* __restrict__ Wfc2, const float* __restrict__ bfc2,
    const float* __restrict__ Wc1, const float* __restrict__ bc1,
    const float* __restrict__ Wc2, const float* __restrict__ bc2,
    const float* __restrict__ lscale, float* __restrict__ out)
{
  __shared__ float sH[512], sI[512], fused[1536], g1[512];
  __shared__ float Lm[20][20], nrm[40];
  const int t = threadIdx.x;
  for (int c=t;c<512;c+=256){ sH[c]=tokH[c]; sI[c]=tokI[c]; }
  __syncthreads();
  for (int j=t;j<512;j+=256){
    float s = bfc2[j];
    for (int r=0;r<512;++r) s += sH[r]*Wfc2[r*512+j];
    for (int r=0;r<512;++r) s += sI[r]*Wfc2[(512+r)*512+j];
    fused[1024+j] = s;                      // concat_tok
  }
  for (int j=t;j<512;j+=256){ fused[j]=sH[j]+sI[j]; fused[512+j]=sH[j]*sI[j]; }
  __syncthreads();
  for (int j=t;j<512;j+=256){
    float s = bc1[j];
    for (int r=0;r<1536;++r) s += fused[r]*Wc1[r*512+j];
    g1[j] = 0.5f*s*(1.0f + erff(s*0.70710678118654752f));
  }
  if (t < 40) {
    const float* rp = (t < 20) ? (atteH + t*512) : (atteI + (t-20)*512);
    float s=0.f;
    for (int r=0;r<512;++r) s += rp[r]*rp[r];
    nrm[t] = sqrtf(s);
  }
  __syncthreads();
  const float scale = expf(lscale[0]);
  for (int e=t;e<400;e+=256){
    const int a2 = e/20, b2 = e%20;
    const float* ra = atteH + a2*512;
    const float* rb = atteI + b2*512;
    float s=0.f;
    for (int r=0;r<512;++r) s += ra[r]*rb[r];
    Lm[a2][b2] = scale * s / (nrm[a2]*nrm[20+b2]);
  }
  __syncthreads();
  if (t < 12) {
    const int c = t & 3, which = t >> 2;
    float s;
    if (which==0){ s=bheC[c]; for(int r=0;r<512;++r) s += sH[r]*WheC[r*4+c]; }
    else if (which==1){ s=bihcC[c]; for(int r=0;r<512;++r) s += sI[r]*WihcC[r*4+c]; }
    else { s=bc2[c]; for(int r=0;r<512;++r) s += g1[r]*Wc2[r*4+c]; }
    out[which*4+c] = s;
  }
  if (t == 0) {
    double total = 0.0;
    for (int half=0; half<2; ++half){
      for (int i=0;i<10;++i) {
        double l1=0.0, l2=0.0;
        for (int j=0;j<10;++j) {
          const double Mji   = half ? (double)Lm[i][j]    : (double)Lm[j][i];
          double mx = Mji;
          for (int q2=10;q2<20;++q2){ const double v = half ? (double)Lm[q2][j] : (double)Lm[j][q2]; if (v>mx) mx=v; }
          double se = exp(Mji-mx);
          for (int q2=10;q2<20;++q2){ const double v = half ? (double)Lm[q2][j] : (double)Lm[j][q2]; se += exp(v-mx); }
          l1 += (log(se)+mx) - Mji;
          const double Mji2 = half ? (double)Lm[10+i][10+j] : (double)Lm[10+j][10+i];
          double mx2 = Mji2;
          for (int q2=0;q2<10;++q2){ const double v = half ? (double)Lm[q2][10+j] : (double)Lm[10+j][q2]; if (v>mx2) mx2=v; }
          double se2 = exp(Mji2-mx2);
          for (int q2=0;q2<10;++q2){ const double v = half ? (double)Lm[q2][10+j] : (double)Lm[10+j][q2]; se2 += exp(v-mx2); }
          l2 += (log(se2)+mx2) - Mji2;
        }
        total += l1*0.1 + l2*0.1;
      }
    }
    const float cl = (float)(total / 40.0);
    out[12]=cl; out[13]=cl; out[14]=cl; out[15]=cl;
  }
}

// ---------------- launcher ----------------
extern "C" void kernel_launch(void* const* d_in, const int* in_sizes, int n_in,
                              void* d_out, int out_size, void* d_ws, size_t ws_size,
                              hipStream_t stream)
{
  (void)in_sizes; (void)n_in; (void)out_size; (void)ws_size;
  auto F = [&](int i){ return (const float*)d_in[i]; };
  char* ws = (char*)d_ws;
  size_t off = 0;
  auto alloc = [&](size_t sz)->void*{ void* p = ws + off; off += (sz + 255) & ~((size_t)255); return p; };

  float* xg   = (float*)alloc((size_t)4096*512*4);   // gelu(fc) output
  float* AX   = (float*)alloc((size_t)512*4096*4);   // Apart, then x_res
  u16*   hhi  = (u16*)alloc((size_t)4096*512*2);
  u16*   hlo  = (u16*)alloc((size_t)4096*512*2);
  u16*   qhi  = (u16*)alloc((size_t)4096*512*2);     // also x-split before fc
  u16*   qlo  = (u16*)alloc((size_t)4096*512*2);
  u16*   khi  = (u16*)alloc((size_t)4096*512*2);
  u16*   klo  = (u16*)alloc((size_t)4096*512*2);
  u16*   vT   = (u16*)alloc((size_t)512*4096*2);     // V transposed [d][n]
  u16*   ov   = (u16*)alloc((size_t)4096*512*2);     // attn output (pre-Wo), bf16
  u16*   wthi = (u16*)alloc((size_t)512*512*2);
  u16*   wtlo = (u16*)alloc((size_t)512*512*2);
  double* A64 = (double*)alloc((size_t)4096*8);
  int*   idxH = (int*)alloc(80);
  int*   idxI = (int*)alloc(80);
  float* spart= (float*)alloc((size_t)64*512*4);
  float* tokH = (float*)alloc(512*4);
  float* tokI = (float*)alloc(512*4);
  float* atteH= (float*)alloc((size_t)20*512*4);
  float* atteI= (float*)alloc((size_t)20*512*4);

  for (int br = 0; br < 2; ++br) {
    const float* x   = F(br?1:0);
    const float* Wfc = F(br?4:2);
    const float* bfc = F(br?5:3);
    const float* lng = F(br?12:6);
    const float* lnb = F(br?13:7);
    const float* Wq  = F(br?14:8);
    const float* Wk  = F(br?15:9);
    const float* Wv  = F(br?16:10);
    const float* Wo  = F(br?17:11);
    int*   idx = br ? idxI : idxH;
    float* tok = br ? tokI : tokH;
    float* att = br ? atteI : atteH;

    k_split_act<<<8192,256,0,stream>>>(x, qhi, qlo, 4096*512);
    k_split_wT<<<1024,256,0,stream>>>(Wfc, wthi, wtlo);
    k_gemm512<3,EPI_GELU><<<dim3(64,8),256,0,stream>>>(qhi,qlo,wthi,wtlo,bfc,nullptr,xg,nullptr,nullptr);
    k_ln_split<<<1024,256,0,stream>>>(xg,lng,lnb,hhi,hlo);
    k_split_wT<<<1024,256,0,stream>>>(Wq, wthi, wtlo);
    k_gemm512<3,EPI_SPLIT><<<dim3(64,8),256,0,stream>>>(hhi,hlo,wthi,wtlo,nullptr,nullptr,nullptr,qhi,qlo);
    k_split_wT<<<1024,256,0,stream>>>(Wk, wthi, wtlo);
    k_gemm512<3,EPI_SPLIT><<<dim3(64,8),256,0,stream>>>(hhi,hlo,wthi,wtlo,nullptr,nullptr,nullptr,khi,klo);
    k_split_wT<<<1024,256,0,stream>>>(Wv, wthi, wtlo);
    k_gemm512<1,EPI_VT><<<dim3(64,8),256,0,stream>>>(hhi,nullptr,wthi,nullptr,nullptr,nullptr,nullptr,vT,nullptr);
    k_attn<<<dim3(64,8),256,0,stream>>>(qhi,qlo,khi,klo,vT,ov,AX);
    k_reduceA<<<16,256,0,stream>>>(AX, A64);
    k_select<<<1,256,0,stream>>>(A64, idx);
    k_split_wT<<<1024,256,0,stream>>>(Wo, wthi, wtlo);
    k_gemm512<1,EPI_RES><<<dim3(64,8),256,0,stream>>>(ov,nullptr,wthi,nullptr,nullptr,xg,AX,nullptr,nullptr);
    k_slide_part<<<64,256,0,stream>>>(AX, spart);
    k_slide_reduce<<<2,256,0,stream>>>(spart, F(18), F(19), tok);
    k_atte<<<20,64,0,stream>>>(AX, idx, F(18), F(19), att);
  }
  k_head<<<1,256,0,stream>>>(tokH,tokI,atteH,atteI,
                             F(20),F(21),F(22),F(23),F(24),F(25),F(26),F(27),F(28),F(29),F(30),
                             (float*)d_out);
}

// Round 2
// 1044.217 us; speedup vs baseline: 1.3752x; 1.3752x over previous
//
#include <hip/hip_runtime.h>
#include <hip/hip_bf16.h>
#include <math.h>

// Problem constants: N=4096, D=512, H=8, DH=64, K_SEL=10, C=4
#define DEV __device__ __forceinline__

typedef __attribute__((ext_vector_type(4))) float  f32x4;
typedef __attribute__((ext_vector_type(8))) short  bf8_t;   // 8 x bf16 (4 VGPRs)
typedef unsigned int   u32;
typedef unsigned short u16;

DEV u16 f2bf(float f){
  u32 u = __builtin_bit_cast(u32, f);
  u32 r = (u + 0x7fffu + ((u >> 16) & 1u)) >> 16;   // RNE
  return (u16)r;
}
DEV float bf2f(u16 h){ u32 u = ((u32)h) << 16; return __builtin_bit_cast(float, u); }
// XOR-swizzle on 16B chunks with row&7 (bank-conflict fix for ds_read_b128)
DEV u32 swzB(u32 r, u32 b, u32 rowBytes){ return r*rowBytes + (b ^ ((r & 7u) << 4)); }

// ---------------- elementwise split kernels ----------------
__global__ void k_split_act(const float* __restrict__ x, u16* __restrict__ hi,
                            u16* __restrict__ lo, int n){
  int i = blockIdx.x*256 + threadIdx.x;
  if (i < n){ float v = x[i]; u16 h = f2bf(v); hi[i]=h; lo[i]=f2bf(v - bf2f(h)); }
}

// W [512][512] fp32 -> transposed split Wt[col][k] bf16 hi/lo
__global__ void k_split_wT(const float* __restrict__ w, u16* __restrict__ thi,
                           u16* __restrict__ tlo){
  int i = blockIdx.x*256 + threadIdx.x;       // over 512*512
  int k = i >> 9, c = i & 511;
  float v = w[i];
  u16 h = f2bf(v);
  thi[c*512 + k] = h;
  tlo[c*512 + k] = f2bf(v - bf2f(h));
}

// ---------------- LayerNorm -> split bf16 ----------------
__global__ __launch_bounds__(256) void k_ln_split(
    const float* __restrict__ x, const float* __restrict__ g, const float* __restrict__ b,
    u16* __restrict__ hhi, u16* __restrict__ hlo)
{
  const int w = threadIdx.x >> 6, lane = threadIdx.x & 63;
  const int row = blockIdx.x*4 + w;
  const float* xr = x + row*512;
  float v[8];
  f32x4 a  = *(const f32x4*)(xr + lane*8);
  f32x4 a2 = *(const f32x4*)(xr + lane*8 + 4);
  v[0]=a.x; v[1]=a.y; v[2]=a.z; v[3]=a.w; v[4]=a2.x; v[5]=a2.y; v[6]=a2.z; v[7]=a2.w;
  float s = v[0]+v[1]+v[2]+v[3]+v[4]+v[5]+v[6]+v[7];
  #pragma unroll
  for (int m=1;m<64;m<<=1) s += __shfl_xor(s, m);
  const float mean = s * (1.0f/512.0f);
  float q = 0.f;
  #pragma unroll
  for (int i=0;i<8;++i){ const float d = v[i]-mean; q += d*d; }
  #pragma unroll
  for (int m=1;m<64;m<<=1) q += __shfl_xor(q, m);
  const float rstd = 1.0f / sqrtf(q*(1.0f/512.0f) + 1e-5f);
  #pragma unroll
  for (int i=0;i<8;++i){
    const int c = lane*8 + i;
    const float y = (v[i]-mean)*rstd*g[c] + b[c];
    const u16 hv = f2bf(y);
    hhi[row*512 + c] = hv;
    hlo[row*512 + c] = f2bf(y - bf2f(hv));
  }
}

// ---------------- generic K=512, N=512 GEMM (M=4096), split-bf16 capable ----------------
enum { EPI_GELU=0, EPI_SPLIT=1, EPI_VT=2, EPI_RES=3 };

template<int TERMS, int EPI>
__global__ __launch_bounds__(256) void k_gemm512(
    const u16* __restrict__ Ahi, const u16* __restrict__ Alo,
    const u16* __restrict__ Bthi, const u16* __restrict__ Btlo,  // transposed weights [col][k]
    const float* __restrict__ bias, const float* __restrict__ resid,
    float* __restrict__ outF, u16* __restrict__ outA, u16* __restrict__ outB)
{
  __shared__ __align__(16) char ls[32768];   // ahi@0 alo@8K bhi@16K blo@24K  ([64][64] bf16 each)
  const int t = threadIdx.x;
  const int w = t >> 6, lane = t & 63;
  const int n0 = blockIdx.x * 64;
  const int c0 = blockIdx.y * 64;
  const int wr = w >> 1, wc = w & 1;
  const int lr = lane & 15, lg = lane >> 4;

  f32x4 acc[2][2];
  #pragma unroll
  for (int i=0;i<2;++i)
    #pragma unroll
    for (int j=0;j<2;++j) acc[i][j] = f32x4{0.f,0.f,0.f,0.f};

  for (int bk = 0; bk < 8; ++bk) {
    const int kb = bk * 64;
    __syncthreads();
    #pragma unroll 2
    for (int i = t; i < 512; i += 256) {
      const int r = i >> 3, c = i & 7;
      const u32 dst = swzB(r, c*16, 128);
      const int ga = (n0 + r)*512 + kb + c*8;
      const int gb = (c0 + r)*512 + kb + c*8;
      *(uint4*)(ls + dst)         = *(const uint4*)(Ahi  + ga);
      *(uint4*)(ls + 16384 + dst) = *(const uint4*)(Bthi + gb);
      if constexpr (TERMS >= 3) {
        *(uint4*)(ls + 8192  + dst) = *(const uint4*)(Alo  + ga);
        *(uint4*)(ls + 24576 + dst) = *(const uint4*)(Btlo + gb);
      }
    }
    __syncthreads();
    #pragma unroll
    for (int ks = 0; ks < 2; ++ks) {
      const u32 co = ks*64 + lg*16;
      bf8_t ah[2], bh[2], al[2], bl[2];
      #pragma unroll
      for (int i=0;i<2;++i) {
        ah[i] = *(const bf8_t*)(ls +         swzB(wr*32 + i*16 + lr, co, 128));
        bh[i] = *(const bf8_t*)(ls + 16384 + swzB(wc*32 + i*16 + lr, co, 128));
        if constexpr (TERMS >= 3) {
          al[i] = *(const bf8_t*)(ls + 8192  + swzB(wr*32 + i*16 + lr, co, 128));
          bl[i] = *(const bf8_t*)(ls + 24576 + swzB(wc*32 + i*16 + lr, co, 128));
        }
      }
      #pragma unroll
      for (int i=0;i<2;++i)
        #pragma unroll
        for (int j=0;j<2;++j) {
          acc[i][j] = __builtin_amdgcn_mfma_f32_16x16x32_bf16(ah[i], bh[j], acc[i][j], 0,0,0);
          if constexpr (TERMS >= 3) {
            acc[i][j] = __builtin_amdgcn_mfma_f32_16x16x32_bf16(ah[i], bl[j], acc[i][j], 0,0,0);
            acc[i][j] = __builtin_amdgcn_mfma_f32_16x16x32_bf16(al[i], bh[j], acc[i][j], 0,0,0);
          }
        }
    }
  }
  #pragma unroll
  for (int i=0;i<2;++i)
    #pragma unroll
    for (int j=0;j<2;++j) {
      const int col = c0 + wc*32 + j*16 + lr;
      #pragma unroll
      for (int r=0;r<4;++r) {
        const int row = n0 + wr*32 + i*16 + lg*4 + r;
        float v = acc[i][j][r];
        if constexpr (EPI == EPI_GELU) {
          v += bias[col];
          outF[row*512 + col] = 0.5f * v * (1.0f + erff(v * 0.70710678118654752f));
        } else if constexpr (EPI == EPI_SPLIT) {
          const u16 hv = f2bf(v);
          outA[row*512 + col] = hv;
          outB[row*512 + col] = f2bf(v - bf2f(hv));
        } else if constexpr (EPI == EPI_VT) {
          outA[col*4096 + row] = f2bf(v);                 // V transposed [d][n]
        } else {
          outF[row*512 + col] = v + resid[row*512 + col]; // residual add
        }
      }
    }
}

// ---------------- fused attention: per (head, 64 q-rows) block ----------------
// pass1: row sum of exp(s) with hi*hi scores; pass2: split scores -> p, colsum partials, P@V
__global__ __launch_bounds__(256) void k_attn(
    const u16* __restrict__ qhi, const u16* __restrict__ qlo,
    const u16* __restrict__ khi, const u16* __restrict__ klo,
    const u16* __restrict__ vt,  u16* __restrict__ ov, float* __restrict__ Apart)
{
  // LDS: 0:qhi[64][64] 8K:qlo 16K:khi[128][64] (P[64][128] alias) 32K:klo 48K... 49152:vt[64][128] (red/rinv alias in pass1)
  __shared__ __align__(16) char ls[65536];
  const int t = threadIdx.x, w = t >> 6, lane = t & 63;
  const int lr = lane & 15, lg = lane >> 4;
  const int nb = blockIdx.x, h = blockIdx.y;
  const int n0 = nb * 64, qc0 = h * 64;
  const float cexp = 0.18033688011112042f;   // log2(e)/8  (scores /sqrt(64))

  for (int i = t; i < 1024; i += 256) {      // stage Q hi/lo
    const int buf = i >> 9, rem = i & 511, r = rem >> 3, c = rem & 7;
    const u16* src = (buf ? qlo : qhi) + (n0 + r)*512 + qc0 + c*8;
    *(uint4*)(ls + buf*8192 + swzB(r, c*16, 128)) = *(const uint4*)src;
  }

  // ---- pass 1: l_n ----
  float rs[16];
  #pragma unroll
  for (int i=0;i<16;++i) rs[i] = 0.f;
  for (int mt = 0; mt < 32; ++mt) {
    const int m0 = mt * 128;
    __syncthreads();
    for (int i = t; i < 1024; i += 256) {
      const int r = i >> 3, c = i & 7;
      *(uint4*)(ls + 16384 + swzB(r, c*16, 128)) = *(const uint4*)(khi + (m0 + r)*512 + qc0 + c*8);
    }
    __syncthreads();
    f32x4 sacc[4][2];
    #pragma unroll
    for (int i=0;i<4;++i){ sacc[i][0]=f32x4{0.f,0.f,0.f,0.f}; sacc[i][1]=f32x4{0.f,0.f,0.f,0.f}; }
    #pragma unroll
    for (int ks=0; ks<2; ++ks) {
      const u32 co = ks*64 + lg*16;
      bf8_t aq[4], bk[2];
      #pragma unroll
      for (int i=0;i<4;++i) aq[i] = *(const bf8_t*)(ls + swzB(i*16 + lr, co, 128));
      #pragma unroll
      for (int j=0;j<2;++j) bk[j] = *(const bf8_t*)(ls + 16384 + swzB(w*32 + j*16 + lr, co, 128));
      #pragma unroll
      for (int i=0;i<4;++i)
        #pragma unroll
        for (int j=0;j<2;++j)
          sacc[i][j] = __builtin_amdgcn_mfma_f32_16x16x32_bf16(aq[i], bk[j], sacc[i][j], 0,0,0);
    }
    #pragma unroll
    for (int i=0;i<4;++i)
      #pragma unroll
      for (int j=0;j<2;++j)
        #pragma unroll
        for (int r=0;r<4;++r)
          rs[i*4+r] += exp2f(sacc[i][j][r] * cexp);
  }
  #pragma unroll
  for (int i=0;i<16;++i){
    float v = rs[i];
    v += __shfl_xor(v, 1); v += __shfl_xor(v, 2);
    v += __shfl_xor(v, 4); v += __shfl_xor(v, 8);
    rs[i] = v;
  }
  __syncthreads();
  if (lr == 0) {
    float* red = (float*)(ls + 49152);
    #pragma unroll
    for (int i=0;i<4;++i)
      #pragma unroll
      for (int r=0;r<4;++r)
        red[w*64 + i*16 + lg*4 + r] = rs[i*4+r];
  }
  __syncthreads();
  if (t < 64) {
    const float* red = (const float*)(ls + 49152);
    const float lsum = red[t] + red[64+t] + red[128+t] + red[192+t];
    ((float*)(ls + 49152 + 1024))[t] = 1.0f / lsum;
  }
  __syncthreads();
  float rv[16];
  #pragma unroll
  for (int i=0;i<4;++i)
    #pragma unroll
    for (int r=0;r<4;++r)
      rv[i*4+r] = ((const float*)(ls + 49152 + 1024))[i*16 + lg*4 + r];

  // ---- pass 2 ----
  f32x4 oacc[4];
  #pragma unroll
  for (int i=0;i<4;++i) oacc[i] = f32x4{0.f,0.f,0.f,0.f};
  for (int mt = 0; mt < 32; ++mt) {
    const int m0 = mt * 128;
    __syncthreads();
    for (int i = t; i < 1024; i += 256) {
      const int r = i >> 3, c = i & 7;
      const u32 dst = swzB(r, c*16, 128);
      const int gk = (m0 + r)*512 + qc0 + c*8;
      *(uint4*)(ls + 16384 + dst) = *(const uint4*)(khi + gk);
      *(uint4*)(ls + 32768 + dst) = *(const uint4*)(klo + gk);
    }
    for (int i = t; i < 1024; i += 256) {
      const int r = i >> 4, c = i & 15;
      *(uint4*)(ls + 49152 + swzB(r, c*16, 256)) = *(const uint4*)(vt + (qc0 + r)*4096 + m0 + c*8);
    }
    __syncthreads();
    f32x4 sacc[4][2];
    #pragma unroll
    for (int i=0;i<4;++i){ sacc[i][0]=f32x4{0.f,0.f,0.f,0.f}; sacc[i][1]=f32x4{0.f,0.f,0.f,0.f}; }
    #pragma unroll
    for (int ks = 0; ks < 2; ++ks) {
      const u32 co = ks*64 + lg*16;
      bf8_t aqh[4], aql[4], bkh[2], bkl[2];
      #pragma unroll
      for (int i=0;i<4;++i){
        aqh[i] = *(const bf8_t*)(ls +        swzB(i*16 + lr, co, 128));
        aql[i] = *(const bf8_t*)(ls + 8192 + swzB(i*16 + lr, co, 128));
      }
      #pragma unroll
      for (int j=0;j<2;++j){
        bkh[j] = *(const bf8_t*)(ls + 16384 + swzB(w*32 + j*16 + lr, co, 128));
        bkl[j] = *(const bf8_t*)(ls + 32768 + swzB(w*32 + j*16 + lr, co, 128));
      }
      #pragma unroll
      for (int i=0;i<4;++i)
        #pragma unroll
        for (int j=0;j<2;++j){
          sacc[i][j] = __builtin_amdgcn_mfma_f32_16x16x32_bf16(aqh[i], bkh[j], sacc[i][j], 0,0,0);
          sacc[i][j] = __builtin_amdgcn_mfma_f32_16x16x32_bf16(aqh[i], bkl[j], sacc[i][j], 0,0,0);
          sacc[i][j] = __builtin_amdgcn_mfma_f32_16x16x32_bf16(aql[i], bkh[j], sacc[i][j], 0,0,0);
        }
    }
    __syncthreads();   // all waves done with K tiles; P may overwrite khi region
    float cs[2] = {0.f, 0.f};
    #pragma unroll
    for (int i=0;i<4;++i)
      #pragma unroll
      for (int j=0;j<2;++j)
        #pragma unroll
        for (int r=0;r<4;++r){
          const float e = exp2f(sacc[i][j][r] * cexp);
          const float p = e * rv[i*4+r];
          cs[j] += p;
          const int prow = i*16 + lg*4 + r;
          const int pcol = w*32 + j*16 + lr;
          *(u16*)(ls + 16384 + swzB(prow, pcol*2, 256)) = f2bf(p);
        }
    #pragma unroll
    for (int j=0;j<2;++j){
      float v = cs[j];
      v += __shfl_xor(v, 16); v += __shfl_xor(v, 32);
      cs[j] = v;
    }
    if (lane < 16) {
      const int base = (h*64 + nb)*4096 + m0 + w*32;
      Apart[base + lane]      = cs[0];
      Apart[base + 16 + lane] = cs[1];
    }
    __syncthreads();   // P fully written
    #pragma unroll
    for (int ks2 = 0; ks2 < 4; ++ks2) {
      const u32 co = ks2*64 + lg*16;
      const bf8_t bv = *(const bf8_t*)(ls + 49152 + swzB(w*16 + lr, co, 256));
      #pragma unroll
      for (int i=0;i<4;++i){
        const bf8_t ap = *(const bf8_t*)(ls + 16384 + swzB(i*16 + lr, co, 256));
        oacc[i] = __builtin_amdgcn_mfma_f32_16x16x32_bf16(ap, bv, oacc[i], 0,0,0);
      }
    }
  }
  #pragma unroll
  for (int i=0;i<4;++i)
    #pragma unroll
    for (int r=0;r<4;++r){
      const int row = n0 + i*16 + lg*4 + r;
      const int col = qc0 + w*16 + lr;
      ov[row*512 + col] = f2bf(oacc[i][r]);
    }
}

// ---------------- A reduction (deterministic fp64) + exact stable-argsort top/bottom-K ----------------
__global__ void k_reduceA(const float* __restrict__ Apart, double* __restrict__ A64){
  const int m = blockIdx.x*256 + threadIdx.x;
  double s = 0.0;
  for (int b=0;b<512;++b) s += (double)Apart[b*4096 + m];
  A64[m] = s;
}

__global__ __launch_bounds__(256) void k_select(const double* __restrict__ A64, int* __restrict__ idx){
  __shared__ double Aw[4096];
  __shared__ double bv[256];
  __shared__ int    bi[256];
  const int t = threadIdx.x;
  for (int i=t;i<4096;i+=256) Aw[i] = A64[i];
  __syncthreads();
  for (int k=0;k<10;++k){                         // top-K: max, tie -> smaller index
    double best = -1e300; int bidx = 1<<30;
    for (int i=t;i<4096;i+=256){
      const double v = Aw[i];
      if (v > best){ best = v; bidx = i; }
    }
    bv[t]=best; bi[t]=bidx;
    __syncthreads();
    for (int s2=128;s2>0;s2>>=1){
      if (t < s2){
        const double v = bv[t+s2]; const int ii = bi[t+s2];
        if (v > bv[t] || (v == bv[t] && ii < bi[t])){ bv[t]=v; bi[t]=ii; }
      }
      __syncthreads();
    }
    if (t==0){ idx[k] = bi[0]; Aw[bi[0]] = -1e300; }
    __syncthreads();
  }
  for (int i=t;i<4096;i+=256) Aw[i] = A64[i];
  __syncthreads();
  for (int k=0;k<10;++k){                         // bottom-K from the end: min, tie -> larger index
    double best = 1e300; int bidx = -1;
    for (int i=t;i<4096;i+=256){
      const double v = Aw[i];
      if (v < best || (v == best && i > bidx)){ best = v; bidx = i; }
    }
    bv[t]=best; bi[t]=bidx;
    __syncthreads();
    for (int s2=128;s2>0;s2>>=1){
      if (t < s2){
        const double v = bv[t+s2]; const int ii = bi[t+s2];
        if (v < bv[t] || (v == bv[t] && ii > bi[t])){ bv[t]=v; bi[t]=ii; }
      }
      __syncthreads();
    }
    if (t==0){ idx[19-k] = bi[0]; Aw[bi[0]] = 1e300; }
    __syncthreads();
  }
}

// ---------------- feats = LN(x_res): mean over rows (partials), and selected rows ----------------
__global__ __launch_bounds__(256) void k_slide_part(const float* __restrict__ xres,
                                                    float* __restrict__ spart){
  __shared__ float acc[4][512];
  const int t = threadIdx.x, w = t >> 6, lane = t & 63;
  float la[8];
  #pragma unroll
  for (int i=0;i<8;++i) la[i]=0.f;
  for (int rr = 0; rr < 16; ++rr) {
    const int row = blockIdx.x*64 + w*16 + rr;
    const float* xr = xres + row*512;
    float v[8];
    f32x4 a  = *(const f32x4*)(xr + lane*8);
    f32x4 a2 = *(const f32x4*)(xr + lane*8 + 4);
    v[0]=a.x; v[1]=a.y; v[2]=a.z; v[3]=a.w; v[4]=a2.x; v[5]=a2.y; v[6]=a2.z; v[7]=a2.w;
    float s = v[0]+v[1]+v[2]+v[3]+v[4]+v[5]+v[6]+v[7];
    #pragma unroll
    for (int m=1;m<64;m<<=1) s += __shfl_xor(s, m);
    const float mean = s * (1.0f/512.0f);
    float q = 0.f;
    #pragma unroll
    for (int i=0;i<8;++i){ const float d = v[i]-mean; q += d*d; }
    #pragma unroll
    for (int m=1;m<64;m<<=1) q += __shfl_xor(q, m);
    const float rstd = 1.0f / sqrtf(q*(1.0f/512.0f) + 1e-5f);
    #pragma unroll
    for (int i=0;i<8;++i) la[i] += (v[i]-mean)*rstd;   // g,b applied at reduce (linear)
  }
  #pragma unroll
  for (int i=0;i<8;++i) acc[w][lane*8+i] = la[i];
  __syncthreads();
  for (int c = t; c < 512; c += 256)
    spart[blockIdx.x*512 + c] = acc[0][c]+acc[1][c]+acc[2][c]+acc[3][c];
}

__global__ void k_slide_reduce(const float* __restrict__ spart, const float* __restrict__ g,
                               const float* __restrict__ b, float* __restrict__ tok){
  const int c = blockIdx.x*256 + threadIdx.x;
  float s = 0.f;
  for (int bb=0;bb<64;++bb) s += spart[bb*512 + c];
  tok[c] = g[c]*(s*(1.0f/4096.0f)) + b[c];
}

__global__ void k_atte(const float* __restrict__ xres, const int* __restrict__ idx,
                       const float* __restrict__ g, const float* __restrict__ b,
                       float* __restrict__ atte){
  const int i = blockIdx.x, lane = threadIdx.x;   // 64 threads = 1 wave
  const int row = idx[i];
  const float* xr = xres + row*512;
  float v[8];
  f32x4 a  = *(const f32x4*)(xr + lane*8);
  f32x4 a2 = *(const f32x4*)(xr + lane*8 + 4);
  v[0]=a.x; v[1]=a.y; v[2]=a.z; v[3]=a.w; v[4]=a2.x; v[5]=a2.y; v[6]=a2.z; v[7]=a2.w;
  float s = v[0]+v[1]+v[2]+v[3]+v[4]+v[5]+v[6]+v[7];
  #pragma unroll
  for (int m=1;m<64;m<<=1) s += __shfl_xor(s, m);
  const float mean = s * (1.0f/512.0f);
  float q = 0.f;
  #pragma unroll
  for (int i2=0;i2<8;++i2){ const float d = v[i2]-mean; q += d*d; }
  #pragma unroll
  for (int m=1;m<64;m<<=1) q += __shfl_xor(q, m);
  const float rstd = 1.0f / sqrtf(q*(1.0f/512.0f) + 1e-5f);
  #pragma unroll
  for (int i2=0;i2<8;++i2){
    const int c = lane*8 + i2;
    atte[i*512 + c] = (v[i2]-mean)*rstd*g[c] + b[c];
  }
}

// ---------------- tiny head: logits + contrastive loss (loss parallelized over 400 tasks) ----------------
__global__ __launch_bounds__(256) void k_head(
    const float* __restrict__ tokH, const float* __restrict__ tokI,
    const float* __restrict__ atteH, const float* __restrict__ atteI,
    const float* __restrict__ WheC, const float* __restrict__ bheC,
    const float* __restrict__ WihcC, const float* __restrict__ bihcC,
    const float* __restrict__ Wfc2, const float* __restrict__ bfc2,
    const float* __restrict__ Wc1, const float* __restrict__ bc1,
    const float* __restrict__ Wc2, const float* __restrict__ bc2,
    const float* __restrict__ lscale, float* __restrict__ out)
{
  __shared__ float sH[512], sI[512], fused[1536], g1[512];
  __shared__ float Lm[20][20], nrm[40];
  __shared__ double terms[512];
  const int t = threadIdx.x;
  for (int c=t;c<512;c+=256){ sH[c]=tokH[c]; sI[c]=tokI[c]; }
  __syncthreads();
  for (int j=t;j<512;j+=256){
    float s = bfc2[j];
    for (int r=0;r<512;++r) s += sH[r]*Wfc2[r*512+j];
    for (int r=0;r<512;++r) s += sI[r]*Wfc2[(512+r)*512+j];
    fused[1024+j] = s;                      // concat_tok
  }
  for (int j=t;j<512;j+=256){ fused[j]=sH[j]+sI[j]; fused[512+j]=sH[j]*sI[j]; }
  __syncthreads();
  for (int j=t;j<512;j+=256){
    float s = bc1[j];
    for (int r=0;r<1536;++r) s += fused[r]*Wc1[r*512+j];
    g1[j] = 0.5f*s*(1.0f + erff(s*0.70710678118654752f));
  }
  if (t < 40) {
    const float* rp = (t < 20) ? (atteH + t*512) : (atteI + (t-20)*512);
    float s=0.f;
    for (int r=0;r<512;++r) s += rp[r]*rp[r];
    nrm[t] = sqrtf(s);
  }
  __syncthreads();
  const float scale = expf(lscale[0]);
  for (int e=t;e<400;e+=256){
    const int a2 = e/20, b2 = e%20;
    const float* ra = atteH + a2*512;
    const float* rb = atteI + b2*512;
    float s=0.f;
    for (int r=0;r<512;++r) s += ra[r]*rb[r];
    Lm[a2][b2] = scale * s / (nrm[a2]*nrm[20+b2]);
  }
  __syncthreads();
  if (t < 12) {
    const int c = t & 3, which = t >> 2;
    float s;
    if (which==0){ s=bheC[c]; for(int r=0;r<512;++r) s += sH[r]*WheC[r*4+c]; }
    else if (which==1){ s=bihcC[c]; for(int r=0;r<512;++r) s += sI[r]*WihcC[r*4+c]; }
    else { s=bc2[c]; for(int r=0;r<512;++r) s += g1[r]*Wc2[r*4+c]; }
    out[which*4+c] = s;
  }
  // ---- contrastive loss: 400 independent logsumexp tasks, fp64, fixed-order reduce ----
  // task e: half=e/200, i=(e/20)%10, part=(e/10)%2, r=e%10
  // Mget(a,b) = half ? Lm[b][a] : Lm[a][b]   (half=1 handles L.T)
  // part0: row a=r       : v0=Mget(r,i),       others Mget(r,10+q)    q=0..9
  // part1: row a=10+r    : v0=Mget(10+r,10+i), others Mget(10+r,q)    q=0..9
  // loss = sum(terms)/400   where term = lse - v0
  for (int e=t;e<512;e+=256){
    double res = 0.0;
    if (e < 400){
      const int r = e % 10, part = (e/10) % 2, i2 = (e/20) % 10, half = e/200;
      const int a = part ? (10 + r) : r;
      const int c0 = part ? (10 + i2) : i2;
      const int qb = part ? 0 : 10;
      auto Mget = [&](int aa, int bb)->double{
        return (double)(half ? Lm[bb][aa] : Lm[aa][bb]);
      };
      const double v0 = Mget(a, c0);
      double mx = v0;
      #pragma unroll
      for (int q=0;q<10;++q){ const double v = Mget(a, qb+q); if (v > mx) mx = v; }
      double se = exp(v0 - mx);
      #pragma unroll
      for (int q=0;q<10;++q) se += exp(Mget(a, qb+q) - mx);
      res = (log(se) + mx) - v0;
    }
    terms[e] = res;
  }
  __syncthreads();
  for (int s2=256;s2>0;s2>>=1){
    if (t < s2) terms[t] += terms[t+s2];
    __syncthreads();
  }
  if (t == 0) {
    const float cl = (float)(terms[0] / 400.0);
    out[12]=cl; out[13]=cl; out[14]=cl; out[15]=cl;
  }
}

// ---------------- launcher ----------------
extern "C" void kernel_launch(void* const* d_in, const int* in_sizes, int n_in,
                              void* d_out, int out_size, void* d_ws, size_t ws_size,
                              hipStream_t stream)
{
  (void)in_sizes; (void)n_in; (void)out_size; (void)ws_size;
  auto F = [&](int i){ return (const float*)d_in[i]; };
  char* ws = (char*)d_ws;
  size_t off = 0;
  auto alloc = [&](size_t sz)->void*{ void* p = ws + off; off += (sz + 255) & ~((size_t)255); return p; };

  float* xg   = (float*)alloc((size_t)4096*512*4);   // gelu(fc) output
  float* AX   = (float*)alloc((size_t)512*4096*4);   // Apart, then x_res
  u16*   hhi  = (u16*)alloc((size_t)4096*512*2);
  u16*   hlo  = (u16*)alloc((size_t)4096*512*2);
  u16*   qhi  = (u16*)alloc((size_t)4096*512*2);     // also x-split before fc
  u16*   qlo  = (u16*)alloc((size_t)4096*512*2);
  u16*   khi  = (u16*)alloc((size_t)4096*512*2);
  u16*   klo  = (u16*)alloc((size_t)4096*512*2);
  u16*   vT   = (u16*)alloc((size_t)512*4096*2);     // V transposed [d][n]
  u16*   ov   = (u16*)alloc((size_t)4096*512*2);     // attn output (pre-Wo), bf16
  u16*   wthi = (u16*)alloc((size_t)512*512*2);
  u16*   wtlo = (u16*)alloc((size_t)512*512*2);
  double* A64 = (double*)alloc((size_t)4096*8);
  int*   idxH = (int*)alloc(80);
  int*   idxI = (int*)alloc(80);
  float* spart= (float*)alloc((size_t)64*512*4);
  float* tokH = (float*)alloc(512*4);
  float* tokI = (float*)alloc(512*4);
  float* atteH= (float*)alloc((size_t)20*512*4);
  float* atteI= (float*)alloc((size_t)20*512*4);

  for (int br = 0; br < 2; ++br) {
    const float* x   = F(br?1:0);
    const float* Wfc = F(br?4:2);
    const float* bfc = F(br?5:3);
    const float* lng = F(br?12:6);
    const float* lnb = F(br?13:7);
    const float* Wq  = F(br?14:8);
    const float* Wk  = F(br?15:9);
    const float* Wv  = F(br?16:10);
    const float* Wo  = F(br?17:11);
    int*   idx = br ? idxI : idxH;
    float* tok = br ? tokI : tokH;
    float* att = br ? atteI : atteH;

    k_split_act<<<8192,256,0,stream>>>(x, qhi, qlo, 4096*512);
    k_split_wT<<<1024,256,0,stream>>>(Wfc, wthi, wtlo);
    k_gemm512<3,EPI_GELU><<<dim3(64,8),256,0,stream>>>(qhi,qlo,wthi,wtlo,bfc,nullptr,xg,nullptr,nullptr);
    k_ln_split<<<1024,256,0,stream>>>(xg,lng,lnb,hhi,hlo);
    k_split_wT<<<1024,256,0,stream>>>(Wq, wthi, wtlo);
    k_gemm512<3,EPI_SPLIT><<<dim3(64,8),256,0,stream>>>(hhi,hlo,wthi,wtlo,nullptr,nullptr,nullptr,qhi,qlo);
    k_split_wT<<<1024,256,0,stream>>>(Wk, wthi, wtlo);
    k_gemm512<3,EPI_SPLIT><<<dim3(64,8),256,0,stream>>>(hhi,hlo,wthi,wtlo,nullptr,nullptr,nullptr,khi,klo);
    k_split_wT<<<1024,256,0,stream>>>(Wv, wthi, wtlo);
    k_gemm512<1,EPI_VT><<<dim3(64,8),256,0,stream>>>(hhi,nullptr,wthi,nullptr,nullptr,nullptr,nullptr,vT,nullptr);
    k_attn<<<dim3(64,8),256,0,stream>>>(qhi,qlo,khi,klo,vT,ov,AX);
    k_reduceA<<<16,256,0,stream>>>(AX, A64);
    k_select<<<1,256,0,stream>>>(A64, idx);
    k_split_wT<<<1024,256,0,stream>>>(Wo, wthi, wtlo);
    k_gemm512<1,EPI_RES><<<dim3(64,8),256,0,stream>>>(ov,nullptr,wthi,nullptr,nullptr,xg,AX,nullptr,nullptr);
    k_slide_part<<<64,256,0,stream>>>(AX, spart);
    k_slide_reduce<<<2,256,0,stream>>>(spart, F(18), F(19), tok);
    k_atte<<<20,64,0,stream>>>(AX, idx, F(18), F(19), att);
  }
  k_head<<<1,256,0,stream>>>(tokH,tokI,atteH,atteI,
                             F(20),F(21),F(22),F(23),F(24),F(25),F(26),F(27),F(28),F(29),F(30),
                             (float*)d_out);
}

// Round 3
// 933.367 us; speedup vs baseline: 1.5385x; 1.1188x over previous
//
#include <hip/hip_runtime.h>
#include <hip/hip_bf16.h>
#include <math.h>

// Problem constants: N=4096, D=512, H=8, DH=64, K_SEL=10, C=4
#define DEV __device__ __forceinline__

typedef __attribute__((ext_vector_type(4))) float  f32x4;
typedef __attribute__((ext_vector_type(8))) short  bf8_t;   // 8 x bf16 (4 VGPRs)
typedef unsigned int   u32;
typedef unsigned short u16;

DEV u16 f2bf(float f){
  u32 u = __builtin_bit_cast(u32, f);
  u32 r = (u + 0x7fffu + ((u >> 16) & 1u)) >> 16;   // RNE
  return (u16)r;
}
DEV float bf2f(u16 h){ u32 u = ((u32)h) << 16; return __builtin_bit_cast(float, u); }
// XOR-swizzle on 16B chunks with row&7 (bank-conflict fix for ds_read_b128)
DEV u32 swzB(u32 r, u32 b, u32 rowBytes){ return r*rowBytes + (b ^ ((r & 7u) << 4)); }

// ---------------- elementwise split kernels ----------------
__global__ void k_split_act(const float* __restrict__ x, u16* __restrict__ hi,
                            u16* __restrict__ lo, int n){
  int i = blockIdx.x*256 + threadIdx.x;
  if (i < n){ float v = x[i]; u16 h = f2bf(v); hi[i]=h; lo[i]=f2bf(v - bf2f(h)); }
}

// W [512][512] fp32 -> transposed split Wt[col][k] bf16 hi/lo
__global__ void k_split_wT(const float* __restrict__ w, u16* __restrict__ thi,
                           u16* __restrict__ tlo){
  int i = blockIdx.x*256 + threadIdx.x;       // over 512*512
  int k = i >> 9, c = i & 511;
  float v = w[i];
  u16 h = f2bf(v);
  thi[c*512 + k] = h;
  tlo[c*512 + k] = f2bf(v - bf2f(h));
}

// ---------------- LayerNorm -> split bf16 ----------------
__global__ __launch_bounds__(256) void k_ln_split(
    const float* __restrict__ x, const float* __restrict__ g, const float* __restrict__ b,
    u16* __restrict__ hhi, u16* __restrict__ hlo)
{
  const int w = threadIdx.x >> 6, lane = threadIdx.x & 63;
  const int row = blockIdx.x*4 + w;
  const float* xr = x + row*512;
  float v[8];
  f32x4 a  = *(const f32x4*)(xr + lane*8);
  f32x4 a2 = *(const f32x4*)(xr + lane*8 + 4);
  v[0]=a.x; v[1]=a.y; v[2]=a.z; v[3]=a.w; v[4]=a2.x; v[5]=a2.y; v[6]=a2.z; v[7]=a2.w;
  float s = v[0]+v[1]+v[2]+v[3]+v[4]+v[5]+v[6]+v[7];
  #pragma unroll
  for (int m=1;m<64;m<<=1) s += __shfl_xor(s, m);
  const float mean = s * (1.0f/512.0f);
  float q = 0.f;
  #pragma unroll
  for (int i=0;i<8;++i){ const float d = v[i]-mean; q += d*d; }
  #pragma unroll
  for (int m=1;m<64;m<<=1) q += __shfl_xor(q, m);
  const float rstd = 1.0f / sqrtf(q*(1.0f/512.0f) + 1e-5f);
  #pragma unroll
  for (int i=0;i<8;++i){
    const int c = lane*8 + i;
    const float y = (v[i]-mean)*rstd*g[c] + b[c];
    const u16 hv = f2bf(y);
    hhi[row*512 + c] = hv;
    hlo[row*512 + c] = f2bf(y - bf2f(hv));
  }
}

// ---------------- generic K=512, N=512 GEMM (M=4096), split-bf16 capable ----------------
enum { EPI_GELU=0, EPI_SPLIT=1, EPI_VT=2, EPI_RES=3 };

template<int TERMS, int EPI>
__global__ __launch_bounds__(256) void k_gemm512(
    const u16* __restrict__ Ahi, const u16* __restrict__ Alo,
    const u16* __restrict__ Bthi, const u16* __restrict__ Btlo,  // transposed weights [col][k]
    const float* __restrict__ bias, const float* __restrict__ resid,
    float* __restrict__ outF, u16* __restrict__ outA, u16* __restrict__ outB)
{
  __shared__ __align__(16) char ls[32768];   // ahi@0 alo@8K bhi@16K blo@24K  ([64][64] bf16 each)
  const int t = threadIdx.x;
  const int w = t >> 6, lane = t & 63;
  const int n0 = blockIdx.x * 64;
  const int c0 = blockIdx.y * 64;
  const int wr = w >> 1, wc = w & 1;
  const int lr = lane & 15, lg = lane >> 4;

  f32x4 acc[2][2];
  #pragma unroll
  for (int i=0;i<2;++i)
    #pragma unroll
    for (int j=0;j<2;++j) acc[i][j] = f32x4{0.f,0.f,0.f,0.f};

  for (int bk = 0; bk < 8; ++bk) {
    const int kb = bk * 64;
    __syncthreads();
    #pragma unroll 2
    for (int i = t; i < 512; i += 256) {
      const int r = i >> 3, c = i & 7;
      const u32 dst = swzB(r, c*16, 128);
      const int ga = (n0 + r)*512 + kb + c*8;
      const int gb = (c0 + r)*512 + kb + c*8;
      *(uint4*)(ls + dst)         = *(const uint4*)(Ahi  + ga);
      *(uint4*)(ls + 16384 + dst) = *(const uint4*)(Bthi + gb);
      if constexpr (TERMS >= 3) {
        *(uint4*)(ls + 8192  + dst) = *(const uint4*)(Alo  + ga);
        *(uint4*)(ls + 24576 + dst) = *(const uint4*)(Btlo + gb);
      }
    }
    __syncthreads();
    #pragma unroll
    for (int ks = 0; ks < 2; ++ks) {
      const u32 co = ks*64 + lg*16;
      bf8_t ah[2], bh[2], al[2], bl[2];
      #pragma unroll
      for (int i=0;i<2;++i) {
        ah[i] = *(const bf8_t*)(ls +         swzB(wr*32 + i*16 + lr, co, 128));
        bh[i] = *(const bf8_t*)(ls + 16384 + swzB(wc*32 + i*16 + lr, co, 128));
        if constexpr (TERMS >= 3) {
          al[i] = *(const bf8_t*)(ls + 8192  + swzB(wr*32 + i*16 + lr, co, 128));
          bl[i] = *(const bf8_t*)(ls + 24576 + swzB(wc*32 + i*16 + lr, co, 128));
        }
      }
      #pragma unroll
      for (int i=0;i<2;++i)
        #pragma unroll
        for (int j=0;j<2;++j) {
          acc[i][j] = __builtin_amdgcn_mfma_f32_16x16x32_bf16(ah[i], bh[j], acc[i][j], 0,0,0);
          if constexpr (TERMS >= 3) {
            acc[i][j] = __builtin_amdgcn_mfma_f32_16x16x32_bf16(ah[i], bl[j], acc[i][j], 0,0,0);
            acc[i][j] = __builtin_amdgcn_mfma_f32_16x16x32_bf16(al[i], bh[j], acc[i][j], 0,0,0);
          }
        }
    }
  }
  #pragma unroll
  for (int i=0;i<2;++i)
    #pragma unroll
    for (int j=0;j<2;++j) {
      const int col = c0 + wc*32 + j*16 + lr;
      #pragma unroll
      for (int r=0;r<4;++r) {
        const int row = n0 + wr*32 + i*16 + lg*4 + r;
        float v = acc[i][j][r];
        if constexpr (EPI == EPI_GELU) {
          v += bias[col];
          outF[row*512 + col] = 0.5f * v * (1.0f + erff(v * 0.70710678118654752f));
        } else if constexpr (EPI == EPI_SPLIT) {
          const u16 hv = f2bf(v);
          outA[row*512 + col] = hv;
          outB[row*512 + col] = f2bf(v - bf2f(hv));
        } else if constexpr (EPI == EPI_VT) {
          outA[col*4096 + row] = f2bf(v);                 // V transposed [d][n]
        } else {
          outF[row*512 + col] = v + resid[row*512 + col]; // residual add
        }
      }
    }
}

// ---------------- fused attention: per (head, 64 q-rows) block ----------------
__global__ __launch_bounds__(256) void k_attn(
    const u16* __restrict__ qhi, const u16* __restrict__ qlo,
    const u16* __restrict__ khi, const u16* __restrict__ klo,
    const u16* __restrict__ vt,  u16* __restrict__ ov, float* __restrict__ Apart)
{
  // LDS: 0:qhi[64][64] 8K:qlo 16K:khi[128][64] (P[64][128] alias) 32K:klo 48K... 49152:vt[64][128] (red/rinv alias in pass1)
  __shared__ __align__(16) char ls[65536];
  const int t = threadIdx.x, w = t >> 6, lane = t & 63;
  const int lr = lane & 15, lg = lane >> 4;
  const int nb = blockIdx.x, h = blockIdx.y;
  const int n0 = nb * 64, qc0 = h * 64;
  const float cexp = 0.18033688011112042f;   // log2(e)/8  (scores /sqrt(64))

  for (int i = t; i < 1024; i += 256) {      // stage Q hi/lo
    const int buf = i >> 9, rem = i & 511, r = rem >> 3, c = rem & 7;
    const u16* src = (buf ? qlo : qhi) + (n0 + r)*512 + qc0 + c*8;
    *(uint4*)(ls + buf*8192 + swzB(r, c*16, 128)) = *(const uint4*)src;
  }

  // ---- pass 1: l_n ----
  float rs[16];
  #pragma unroll
  for (int i=0;i<16;++i) rs[i] = 0.f;
  for (int mt = 0; mt < 32; ++mt) {
    const int m0 = mt * 128;
    __syncthreads();
    for (int i = t; i < 1024; i += 256) {
      const int r = i >> 3, c = i & 7;
      *(uint4*)(ls + 16384 + swzB(r, c*16, 128)) = *(const uint4*)(khi + (m0 + r)*512 + qc0 + c*8);
    }
    __syncthreads();
    f32x4 sacc[4][2];
    #pragma unroll
    for (int i=0;i<4;++i){ sacc[i][0]=f32x4{0.f,0.f,0.f,0.f}; sacc[i][1]=f32x4{0.f,0.f,0.f,0.f}; }
    #pragma unroll
    for (int ks=0; ks<2; ++ks) {
      const u32 co = ks*64 + lg*16;
      bf8_t aq[4], bk[2];
      #pragma unroll
      for (int i=0;i<4;++i) aq[i] = *(const bf8_t*)(ls + swzB(i*16 + lr, co, 128));
      #pragma unroll
      for (int j=0;j<2;++j) bk[j] = *(const bf8_t*)(ls + 16384 + swzB(w*32 + j*16 + lr, co, 128));
      #pragma unroll
      for (int i=0;i<4;++i)
        #pragma unroll
        for (int j=0;j<2;++j)
          sacc[i][j] = __builtin_amdgcn_mfma_f32_16x16x32_bf16(aq[i], bk[j], sacc[i][j], 0,0,0);
    }
    #pragma unroll
    for (int i=0;i<4;++i)
      #pragma unroll
      for (int j=0;j<2;++j)
        #pragma unroll
        for (int r=0;r<4;++r)
          rs[i*4+r] += exp2f(sacc[i][j][r] * cexp);
  }
  #pragma unroll
  for (int i=0;i<16;++i){
    float v = rs[i];
    v += __shfl_xor(v, 1); v += __shfl_xor(v, 2);
    v += __shfl_xor(v, 4); v += __shfl_xor(v, 8);
    rs[i] = v;
  }
  __syncthreads();
  if (lr == 0) {
    float* red = (float*)(ls + 49152);
    #pragma unroll
    for (int i=0;i<4;++i)
      #pragma unroll
      for (int r=0;r<4;++r)
        red[w*64 + i*16 + lg*4 + r] = rs[i*4+r];
  }
  __syncthreads();
  if (t < 64) {
    const float* red = (const float*)(ls + 49152);
    const float lsum = red[t] + red[64+t] + red[128+t] + red[192+t];
    ((float*)(ls + 49152 + 1024))[t] = 1.0f / lsum;
  }
  __syncthreads();
  float rv[16];
  #pragma unroll
  for (int i=0;i<4;++i)
    #pragma unroll
    for (int r=0;r<4;++r)
      rv[i*4+r] = ((const float*)(ls + 49152 + 1024))[i*16 + lg*4 + r];

  // ---- pass 2 ----
  f32x4 oacc[4];
  #pragma unroll
  for (int i=0;i<4;++i) oacc[i] = f32x4{0.f,0.f,0.f,0.f};
  for (int mt = 0; mt < 32; ++mt) {
    const int m0 = mt * 128;
    __syncthreads();
    for (int i = t; i < 1024; i += 256) {
      const int r = i >> 3, c = i & 7;
      const u32 dst = swzB(r, c*16, 128);
      const int gk = (m0 + r)*512 + qc0 + c*8;
      *(uint4*)(ls + 16384 + dst) = *(const uint4*)(khi + gk);
      *(uint4*)(ls + 32768 + dst) = *(const uint4*)(klo + gk);
    }
    for (int i = t; i < 1024; i += 256) {
      const int r = i >> 4, c = i & 15;
      *(uint4*)(ls + 49152 + swzB(r, c*16, 256)) = *(const uint4*)(vt + (qc0 + r)*4096 + m0 + c*8);
    }
    __syncthreads();
    f32x4 sacc[4][2];
    #pragma unroll
    for (int i=0;i<4;++i){ sacc[i][0]=f32x4{0.f,0.f,0.f,0.f}; sacc[i][1]=f32x4{0.f,0.f,0.f,0.f}; }
    #pragma unroll
    for (int ks = 0; ks < 2; ++ks) {
      const u32 co = ks*64 + lg*16;
      bf8_t aqh[4], aql[4], bkh[2], bkl[2];
      #pragma unroll
      for (int i=0;i<4;++i){
        aqh[i] = *(const bf8_t*)(ls +        swzB(i*16 + lr, co, 128));
        aql[i] = *(const bf8_t*)(ls + 8192 + swzB(i*16 + lr, co, 128));
      }
      #pragma unroll
      for (int j=0;j<2;++j){
        bkh[j] = *(const bf8_t*)(ls + 16384 + swzB(w*32 + j*16 + lr, co, 128));
        bkl[j] = *(const bf8_t*)(ls + 32768 + swzB(w*32 + j*16 + lr, co, 128));
      }
      #pragma unroll
      for (int i=0;i<4;++i)
        #pragma unroll
        for (int j=0;j<2;++j){
          sacc[i][j] = __builtin_amdgcn_mfma_f32_16x16x32_bf16(aqh[i], bkh[j], sacc[i][j], 0,0,0);
          sacc[i][j] = __builtin_amdgcn_mfma_f32_16x16x32_bf16(aqh[i], bkl[j], sacc[i][j], 0,0,0);
          sacc[i][j] = __builtin_amdgcn_mfma_f32_16x16x32_bf16(aql[i], bkh[j], sacc[i][j], 0,0,0);
        }
    }
    __syncthreads();   // all waves done with K tiles; P may overwrite khi region
    float cs[2] = {0.f, 0.f};
    #pragma unroll
    for (int i=0;i<4;++i)
      #pragma unroll
      for (int j=0;j<2;++j)
        #pragma unroll
        for (int r=0;r<4;++r){
          const float e = exp2f(sacc[i][j][r] * cexp);
          const float p = e * rv[i*4+r];
          cs[j] += p;
          const int prow = i*16 + lg*4 + r;
          const int pcol = w*32 + j*16 + lr;
          *(u16*)(ls + 16384 + swzB(prow, pcol*2, 256)) = f2bf(p);
        }
    #pragma unroll
    for (int j=0;j<2;++j){
      float v = cs[j];
      v += __shfl_xor(v, 16); v += __shfl_xor(v, 32);
      cs[j] = v;
    }
    if (lane < 16) {
      const int base = (h*64 + nb)*4096 + m0 + w*32;
      Apart[base + lane]      = cs[0];
      Apart[base + 16 + lane] = cs[1];
    }
    __syncthreads();   // P fully written
    #pragma unroll
    for (int ks2 = 0; ks2 < 4; ++ks2) {
      const u32 co = ks2*64 + lg*16;
      const bf8_t bv = *(const bf8_t*)(ls + 49152 + swzB(w*16 + lr, co, 256));
      #pragma unroll
      for (int i=0;i<4;++i){
        const bf8_t ap = *(const bf8_t*)(ls + 16384 + swzB(i*16 + lr, co, 256));
        oacc[i] = __builtin_amdgcn_mfma_f32_16x16x32_bf16(ap, bv, oacc[i], 0,0,0);
      }
    }
  }
  #pragma unroll
  for (int i=0;i<4;++i)
    #pragma unroll
    for (int r=0;r<4;++r){
      const int row = n0 + i*16 + lg*4 + r;
      const int col = qc0 + w*16 + lr;
      ov[row*512 + col] = f2bf(oacc[i][r]);
    }
}

// ---------------- A reduction (deterministic fp64) + exact stable-argsort top/bottom-K ----------------
__global__ void k_reduceA(const float* __restrict__ Apart, double* __restrict__ A64){
  const int m = blockIdx.x*256 + threadIdx.x;
  double s = 0.0;
  for (int b=0;b<512;++b) s += (double)Apart[b*4096 + m];
  A64[m] = s;
}

__global__ __launch_bounds__(256) void k_select(const double* __restrict__ A64, int* __restrict__ idx){
  __shared__ double Aw[4096];
  __shared__ double bv[256];
  __shared__ int    bi[256];
  const int t = threadIdx.x;
  for (int i=t;i<4096;i+=256) Aw[i] = A64[i];
  __syncthreads();
  for (int k=0;k<10;++k){                         // top-K: max, tie -> smaller index
    double best = -1e300; int bidx = 1<<30;
    for (int i=t;i<4096;i+=256){
      const double v = Aw[i];
      if (v > best){ best = v; bidx = i; }
    }
    bv[t]=best; bi[t]=bidx;
    __syncthreads();
    for (int s2=128;s2>0;s2>>=1){
      if (t < s2){
        const double v = bv[t+s2]; const int ii = bi[t+s2];
        if (v > bv[t] || (v == bv[t] && ii < bi[t])){ bv[t]=v; bi[t]=ii; }
      }
      __syncthreads();
    }
    if (t==0){ idx[k] = bi[0]; Aw[bi[0]] = -1e300; }
    __syncthreads();
  }
  for (int i=t;i<4096;i+=256) Aw[i] = A64[i];
  __syncthreads();
  for (int k=0;k<10;++k){                         // bottom-K from the end: min, tie -> larger index
    double best = 1e300; int bidx = -1;
    for (int i=t;i<4096;i+=256){
      const double v = Aw[i];
      if (v < best || (v == best && i > bidx)){ best = v; bidx = i; }
    }
    bv[t]=best; bi[t]=bidx;
    __syncthreads();
    for (int s2=128;s2>0;s2>>=1){
      if (t < s2){
        const double v = bv[t+s2]; const int ii = bi[t+s2];
        if (v < bv[t] || (v == bv[t] && ii > bi[t])){ bv[t]=v; bi[t]=ii; }
      }
      __syncthreads();
    }
    if (t==0){ idx[19-k] = bi[0]; Aw[bi[0]] = 1e300; }
    __syncthreads();
  }
}

// ---------------- feats = LN(x_res): mean over rows (partials), and selected rows ----------------
__global__ __launch_bounds__(256) void k_slide_part(const float* __restrict__ xres,
                                                    float* __restrict__ spart){
  __shared__ float acc[4][512];
  const int t = threadIdx.x, w = t >> 6, lane = t & 63;
  float la[8];
  #pragma unroll
  for (int i=0;i<8;++i) la[i]=0.f;
  for (int rr = 0; rr < 16; ++rr) {
    const int row = blockIdx.x*64 + w*16 + rr;
    const float* xr = xres + row*512;
    float v[8];
    f32x4 a  = *(const f32x4*)(xr + lane*8);
    f32x4 a2 = *(const f32x4*)(xr + lane*8 + 4);
    v[0]=a.x; v[1]=a.y; v[2]=a.z; v[3]=a.w; v[4]=a2.x; v[5]=a2.y; v[6]=a2.z; v[7]=a2.w;
    float s = v[0]+v[1]+v[2]+v[3]+v[4]+v[5]+v[6]+v[7];
    #pragma unroll
    for (int m=1;m<64;m<<=1) s += __shfl_xor(s, m);
    const float mean = s * (1.0f/512.0f);
    float q = 0.f;
    #pragma unroll
    for (int i=0;i<8;++i){ const float d = v[i]-mean; q += d*d; }
    #pragma unroll
    for (int m=1;m<64;m<<=1) q += __shfl_xor(q, m);
    const float rstd = 1.0f / sqrtf(q*(1.0f/512.0f) + 1e-5f);
    #pragma unroll
    for (int i=0;i<8;++i) la[i] += (v[i]-mean)*rstd;   // g,b applied at reduce (linear)
  }
  #pragma unroll
  for (int i=0;i<8;++i) acc[w][lane*8+i] = la[i];
  __syncthreads();
  for (int c = t; c < 512; c += 256)
    spart[blockIdx.x*512 + c] = acc[0][c]+acc[1][c]+acc[2][c]+acc[3][c];
}

__global__ void k_slide_reduce(const float* __restrict__ spart, const float* __restrict__ g,
                               const float* __restrict__ b, float* __restrict__ tok){
  const int c = blockIdx.x*256 + threadIdx.x;
  float s = 0.f;
  for (int bb=0;bb<64;++bb) s += spart[bb*512 + c];
  tok[c] = g[c]*(s*(1.0f/4096.0f)) + b[c];
}

__global__ void k_atte(const float* __restrict__ xres, const int* __restrict__ idx,
                       const float* __restrict__ g, const float* __restrict__ b,
                       float* __restrict__ atte){
  const int i = blockIdx.x, lane = threadIdx.x;   // 64 threads = 1 wave
  const int row = idx[i];
  const float* xr = xres + row*512;
  float v[8];
  f32x4 a  = *(const f32x4*)(xr + lane*8);
  f32x4 a2 = *(const f32x4*)(xr + lane*8 + 4);
  v[0]=a.x; v[1]=a.y; v[2]=a.z; v[3]=a.w; v[4]=a2.x; v[5]=a2.y; v[6]=a2.z; v[7]=a2.w;
  float s = v[0]+v[1]+v[2]+v[3]+v[4]+v[5]+v[6]+v[7];
  #pragma unroll
  for (int m=1;m<64;m<<=1) s += __shfl_xor(s, m);
  const float mean = s * (1.0f/512.0f);
  float q = 0.f;
  #pragma unroll
  for (int i2=0;i2<8;++i2){ const float d = v[i2]-mean; q += d*d; }
  #pragma unroll
  for (int m=1;m<64;m<<=1) q += __shfl_xor(q, m);
  const float rstd = 1.0f / sqrtf(q*(1.0f/512.0f) + 1e-5f);
  #pragma unroll
  for (int i2=0;i2<8;++i2){
    const int c = lane*8 + i2;
    atte[i*512 + c] = (v[i2]-mean)*rstd*g[c] + b[c];
  }
}

// ---------------- head stage 1: concat GEMV (Wfc2 [1024][512]) + elementwise fused parts ----------------
__global__ __launch_bounds__(256) void k_fused(
    const float* __restrict__ tokH, const float* __restrict__ tokI,
    const float* __restrict__ Wfc2, const float* __restrict__ bfc2,
    float* __restrict__ fused)
{
  __shared__ float part[8][32];
  const int t = threadIdx.x;
  const int jj = t & 31, rg = t >> 5;
  const int j = blockIdx.x*32 + jj;
  float s = 0.f;
  for (int r = rg; r < 1024; r += 8){
    const float xv = (r < 512) ? tokH[r] : tokI[r-512];
    s += xv * Wfc2[r*512 + j];
  }
  part[rg][jj] = s;
  __syncthreads();
  if (t < 32){
    const int jo = blockIdx.x*32 + t;
    float acc = bfc2[jo];
    #pragma unroll
    for (int g=0; g<8; ++g) acc += part[g][t];
    const float hv = tokH[jo], iv = tokI[jo];
    fused[jo]        = hv + iv;
    fused[512 + jo]  = hv * iv;
    fused[1024 + jo] = acc;
  }
}

// ---------------- head stage 2: g1 = gelu(fused @ Wc1 + bc1), Wc1 [1536][512] ----------------
__global__ __launch_bounds__(256) void k_g1(
    const float* __restrict__ fused, const float* __restrict__ Wc1,
    const float* __restrict__ bc1, float* __restrict__ g1)
{
  __shared__ float part[8][32];
  const int t = threadIdx.x;
  const int jj = t & 31, rg = t >> 5;
  const int j = blockIdx.x*32 + jj;
  float s = 0.f;
  for (int r = rg; r < 1536; r += 8)
    s += fused[r] * Wc1[r*512 + j];
  part[rg][jj] = s;
  __syncthreads();
  if (t < 32){
    const int jo = blockIdx.x*32 + t;
    float acc = bc1[jo];
    #pragma unroll
    for (int g=0; g<8; ++g) acc += part[g][t];
    g1[jo] = 0.5f*acc*(1.0f + erff(acc*0.70710678118654752f));
  }
}

// ---------------- head stage 3: Lm[20][20] cosine-sim matrix ----------------
__global__ __launch_bounds__(256) void k_lm(
    const float* __restrict__ atteH, const float* __restrict__ atteI,
    const float* __restrict__ lscale, float* __restrict__ Lm)
{
  __shared__ float ra[512];
  __shared__ float nAs;
  const int a = blockIdx.x, t = threadIdx.x, w = t >> 6, l = t & 63;
  for (int i=t;i<512;i+=256) ra[i] = atteH[a*512+i];
  __syncthreads();
  if (w == 0){
    float s = 0.f;
    #pragma unroll
    for (int k=0;k<8;++k){ const float v = ra[l + k*64]; s += v*v; }
    #pragma unroll
    for (int m=1;m<64;m<<=1) s += __shfl_xor(s, m);
    if (l == 0) nAs = s;
  }
  __syncthreads();
  const float scale = expf(lscale[0]);
  const float nA = sqrtf(nAs);
  for (int bi = 0; bi < 5; ++bi){
    const int b = w + bi*4;
    float dot = 0.f, nb = 0.f;
    #pragma unroll
    for (int k=0;k<8;++k){
      const float vb = atteI[b*512 + l + k*64];
      dot += ra[l + k*64]*vb;
      nb  += vb*vb;
    }
    #pragma unroll
    for (int m=1;m<64;m<<=1){ dot += __shfl_xor(dot,m); nb += __shfl_xor(nb,m); }
    if (l == 0) Lm[a*20 + b] = scale * dot / (nA * sqrtf(nb));
  }
}

// ---------------- head stage 4: classifier logits + contrastive loss ----------------
__global__ __launch_bounds__(256) void k_loss(
    const float* __restrict__ tokH, const float* __restrict__ tokI,
    const float* __restrict__ g1G, const float* __restrict__ LmG,
    const float* __restrict__ WheC, const float* __restrict__ bheC,
    const float* __restrict__ WihcC, const float* __restrict__ bihcC,
    const float* __restrict__ Wc2, const float* __restrict__ bc2,
    float* __restrict__ out)
{
  __shared__ float sH[512], sI[512], g1[512];
  __shared__ float Lm[20][20];
  __shared__ double terms[512];
  const int t = threadIdx.x, w = t >> 6, l = t & 63;
  for (int i=t;i<512;i+=256){ sH[i]=tokH[i]; sI[i]=tokI[i]; g1[i]=g1G[i]; }
  for (int i=t;i<400;i+=256) ((float*)Lm)[i] = LmG[i];
  __syncthreads();
  // logits: wave w in {0,1,2} computes one 4-wide GEMV with coalesced W reads
  if (w < 3){
    const float* x  = (w==0)? sH   : (w==1)? sI    : g1;
    const float* W  = (w==0)? WheC : (w==1)? WihcC : Wc2;
    const float* bb = (w==0)? bheC : (w==1)? bihcC : bc2;
    const int c = l & 3, rg = l >> 2;
    float s = 0.f;
    for (int r = rg; r < 512; r += 16) s += x[r]*W[r*4+c];
    #pragma unroll
    for (int m=4;m<64;m<<=1) s += __shfl_xor(s, m);
    if (rg == 0) out[w*4 + c] = s + bb[c];
  }
  // contrastive loss: 400 independent logsumexp tasks, fp64, fixed-order reduce
  for (int e=t;e<512;e+=256){
    double res = 0.0;
    if (e < 400){
      const int r = e % 10, part = (e/10) % 2, i2 = (e/20) % 10, half = e/200;
      const int a = part ? (10 + r) : r;
      const int c0 = part ? (10 + i2) : i2;
      const int qb = part ? 0 : 10;
      auto Mget = [&](int aa, int bb)->double{
        return (double)(half ? Lm[bb][aa] : Lm[aa][bb]);
      };
      const double v0 = Mget(a, c0);
      double mx = v0;
      #pragma unroll
      for (int q=0;q<10;++q){ const double v = Mget(a, qb+q); if (v > mx) mx = v; }
      double se = exp(v0 - mx);
      #pragma unroll
      for (int q=0;q<10;++q) se += exp(Mget(a, qb+q) - mx);
      res = (log(se) + mx) - v0;
    }
    terms[e] = res;
  }
  __syncthreads();
  for (int s2=256;s2>0;s2>>=1){
    if (t < s2) terms[t] += terms[t+s2];
    __syncthreads();
  }
  if (t == 0) {
    const float cl = (float)(terms[0] / 400.0);
    out[12]=cl; out[13]=cl; out[14]=cl; out[15]=cl;
  }
}

// ---------------- launcher ----------------
extern "C" void kernel_launch(void* const* d_in, const int* in_sizes, int n_in,
                              void* d_out, int out_size, void* d_ws, size_t ws_size,
                              hipStream_t stream)
{
  (void)in_sizes; (void)n_in; (void)out_size; (void)ws_size;
  auto F = [&](int i){ return (const float*)d_in[i]; };
  char* ws = (char*)d_ws;
  size_t off = 0;
  auto alloc = [&](size_t sz)->void*{ void* p = ws + off; off += (sz + 255) & ~((size_t)255); return p; };

  float* xg   = (float*)alloc((size_t)4096*512*4);   // gelu(fc) output
  float* AX   = (float*)alloc((size_t)512*4096*4);   // Apart, then x_res
  u16*   hhi  = (u16*)alloc((size_t)4096*512*2);
  u16*   hlo  = (u16*)alloc((size_t)4096*512*2);
  u16*   qhi  = (u16*)alloc((size_t)4096*512*2);     // also x-split before fc
  u16*   qlo  = (u16*)alloc((size_t)4096*512*2);
  u16*   khi  = (u16*)alloc((size_t)4096*512*2);
  u16*   klo  = (u16*)alloc((size_t)4096*512*2);
  u16*   vT   = (u16*)alloc((size_t)512*4096*2);     // V transposed [d][n]
  u16*   ov   = (u16*)alloc((size_t)4096*512*2);     // attn output (pre-Wo), bf16
  u16*   wthi = (u16*)alloc((size_t)512*512*2);
  u16*   wtlo = (u16*)alloc((size_t)512*512*2);
  double* A64 = (double*)alloc((size_t)4096*8);
  int*   idxH = (int*)alloc(80);
  int*   idxI = (int*)alloc(80);
  float* spart= (float*)alloc((size_t)64*512*4);
  float* tokH = (float*)alloc(512*4);
  float* tokI = (float*)alloc(512*4);
  float* atteH= (float*)alloc((size_t)20*512*4);
  float* atteI= (float*)alloc((size_t)20*512*4);
  float* fusedW = (float*)alloc(1536*4);
  float* g1W    = (float*)alloc(512*4);
  float* LmW    = (float*)alloc(400*4);

  for (int br = 0; br < 2; ++br) {
    const float* x   = F(br?1:0);
    const float* Wfc = F(br?4:2);
    const float* bfc = F(br?5:3);
    const float* lng = F(br?12:6);
    const float* lnb = F(br?13:7);
    const float* Wq  = F(br?14:8);
    const float* Wk  = F(br?15:9);
    const float* Wv  = F(br?16:10);
    const float* Wo  = F(br?17:11);
    int*   idx = br ? idxI : idxH;
    float* tok = br ? tokI : tokH;
    float* att = br ? atteI : atteH;

    k_split_act<<<8192,256,0,stream>>>(x, qhi, qlo, 4096*512);
    k_split_wT<<<1024,256,0,stream>>>(Wfc, wthi, wtlo);
    k_gemm512<3,EPI_GELU><<<dim3(64,8),256,0,stream>>>(qhi,qlo,wthi,wtlo,bfc,nullptr,xg,nullptr,nullptr);
    k_ln_split<<<1024,256,0,stream>>>(xg,lng,lnb,hhi,hlo);
    k_split_wT<<<1024,256,0,stream>>>(Wq, wthi, wtlo);
    k_gemm512<3,EPI_SPLIT><<<dim3(64,8),256,0,stream>>>(hhi,hlo,wthi,wtlo,nullptr,nullptr,nullptr,qhi,qlo);
    k_split_wT<<<1024,256,0,stream>>>(Wk, wthi, wtlo);
    k_gemm512<3,EPI_SPLIT><<<dim3(64,8),256,0,stream>>>(hhi,hlo,wthi,wtlo,nullptr,nullptr,nullptr,khi,klo);
    k_split_wT<<<1024,256,0,stream>>>(Wv, wthi, wtlo);
    k_gemm512<1,EPI_VT><<<dim3(64,8),256,0,stream>>>(hhi,nullptr,wthi,nullptr,nullptr,nullptr,nullptr,vT,nullptr);
    k_attn<<<dim3(64,8),256,0,stream>>>(qhi,qlo,khi,klo,vT,ov,AX);
    k_reduceA<<<16,256,0,stream>>>(AX, A64);
    k_select<<<1,256,0,stream>>>(A64, idx);
    k_split_wT<<<1024,256,0,stream>>>(Wo, wthi, wtlo);
    k_gemm512<1,EPI_RES><<<dim3(64,8),256,0,stream>>>(ov,nullptr,wthi,nullptr,nullptr,xg,AX,nullptr,nullptr);
    k_slide_part<<<64,256,0,stream>>>(AX, spart);
    k_slide_reduce<<<2,256,0,stream>>>(spart, F(18), F(19), tok);
    k_atte<<<20,64,0,stream>>>(AX, idx, F(18), F(19), att);
  }
  k_fused<<<16,256,0,stream>>>(tokH, tokI, F(24), F(25), fusedW);
  k_g1<<<16,256,0,stream>>>(fusedW, F(26), F(27), g1W);
  k_lm<<<20,256,0,stream>>>(atteH, atteI, F(30), LmW);
  k_loss<<<1,256,0,stream>>>(tokH, tokI, g1W, LmW,
                             F(20), F(21), F(22), F(23), F(28), F(29),
                             (float*)d_out);
}

// Round 4
// 703.213 us; speedup vs baseline: 2.0420x; 1.3273x over previous
//
#include <hip/hip_runtime.h>
#include <hip/hip_bf16.h>
#include <math.h>

// Problem constants: N=4096, D=512, H=8, DH=64, K_SEL=10, C=4
#define DEV __device__ __forceinline__

typedef __attribute__((ext_vector_type(4))) float  f32x4;
typedef __attribute__((ext_vector_type(8))) short  bf8_t;   // 8 x bf16 (4 VGPRs)
typedef unsigned int   u32;
typedef unsigned short u16;

DEV u16 f2bf(float f){
  u32 u = __builtin_bit_cast(u32, f);
  u32 r = (u + 0x7fffu + ((u >> 16) & 1u)) >> 16;   // RNE
  return (u16)r;
}
DEV float bf2f(u16 h){ u32 u = ((u32)h) << 16; return __builtin_bit_cast(float, u); }
// XOR-swizzle on 16B chunks with row&7 (bank-conflict fix for ds_read_b128)
DEV u32 swzB(u32 r, u32 b, u32 rowBytes){ return r*rowBytes + (b ^ ((r & 7u) << 4)); }

// ---------------- elementwise split kernels ----------------
__global__ void k_split_act(const float* __restrict__ x, u16* __restrict__ hi,
                            u16* __restrict__ lo, int n){
  int i = blockIdx.x*256 + threadIdx.x;
  if (i < n){ float v = x[i]; u16 h = f2bf(v); hi[i]=h; lo[i]=f2bf(v - bf2f(h)); }
}

// 5 weight matrices [512][512] fp32 -> transposed split bf16; lo only for first 3 (fc,q,k)
__global__ void k_split_w5(const float* __restrict__ W0, const float* __restrict__ W1,
                           const float* __restrict__ W2, const float* __restrict__ W3,
                           const float* __restrict__ W4, u16* __restrict__ ob){
  const int which = blockIdx.y;
  const float* w = (which==0)?W0:(which==1)?W1:(which==2)?W2:(which==3)?W3:W4;
  int i = blockIdx.x*256 + threadIdx.x;       // over 512*512
  int k = i >> 9, c = i & 511;
  float v = w[i];
  u16 h = f2bf(v);
  u16* thi = ob + which*524288;
  thi[c*512 + k] = h;
  if (which < 3) thi[262144 + c*512 + k] = f2bf(v - bf2f(h));
}

// ---------------- LayerNorm -> split bf16 ----------------
__global__ __launch_bounds__(256) void k_ln_split(
    const float* __restrict__ x, const float* __restrict__ g, const float* __restrict__ b,
    u16* __restrict__ hhi, u16* __restrict__ hlo)
{
  const int w = threadIdx.x >> 6, lane = threadIdx.x & 63;
  const int row = blockIdx.x*4 + w;
  const float* xr = x + row*512;
  float v[8];
  f32x4 a  = *(const f32x4*)(xr + lane*8);
  f32x4 a2 = *(const f32x4*)(xr + lane*8 + 4);
  v[0]=a.x; v[1]=a.y; v[2]=a.z; v[3]=a.w; v[4]=a2.x; v[5]=a2.y; v[6]=a2.z; v[7]=a2.w;
  float s = v[0]+v[1]+v[2]+v[3]+v[4]+v[5]+v[6]+v[7];
  #pragma unroll
  for (int m=1;m<64;m<<=1) s += __shfl_xor(s, m);
  const float mean = s * (1.0f/512.0f);
  float q = 0.f;
  #pragma unroll
  for (int i=0;i<8;++i){ const float d = v[i]-mean; q += d*d; }
  #pragma unroll
  for (int m=1;m<64;m<<=1) q += __shfl_xor(q, m);
  const float rstd = 1.0f / sqrtf(q*(1.0f/512.0f) + 1e-5f);
  #pragma unroll
  for (int i=0;i<8;++i){
    const int c = lane*8 + i;
    const float y = (v[i]-mean)*rstd*g[c] + b[c];
    const u16 hv = f2bf(y);
    hhi[row*512 + c] = hv;
    hlo[row*512 + c] = f2bf(y - bf2f(hv));
  }
}

// ---------------- generic K=512, N=512 GEMM (M=4096), split-bf16 capable ----------------
enum { EPI_GELU=0, EPI_BF16=1, EPI_VT=2, EPI_RES=3 };

template<int TERMS, int EPI>
__global__ __launch_bounds__(256) void k_gemm512(
    const u16* __restrict__ Ahi, const u16* __restrict__ Alo,
    const u16* __restrict__ Bthi, const u16* __restrict__ Btlo,  // transposed weights [col][k]
    const float* __restrict__ bias, const float* __restrict__ resid,
    float* __restrict__ outF, u16* __restrict__ outA)
{
  __shared__ __align__(16) char ls[32768];   // ahi@0 alo@8K bhi@16K blo@24K  ([64][64] bf16 each)
  const int t = threadIdx.x;
  const int w = t >> 6, lane = t & 63;
  const int n0 = blockIdx.x * 64;
  const int c0 = blockIdx.y * 64;
  const int wr = w >> 1, wc = w & 1;
  const int lr = lane & 15, lg = lane >> 4;

  f32x4 acc[2][2];
  #pragma unroll
  for (int i=0;i<2;++i)
    #pragma unroll
    for (int j=0;j<2;++j) acc[i][j] = f32x4{0.f,0.f,0.f,0.f};

  for (int bk = 0; bk < 8; ++bk) {
    const int kb = bk * 64;
    __syncthreads();
    #pragma unroll 2
    for (int i = t; i < 512; i += 256) {
      const int r = i >> 3, c = i & 7;
      const u32 dst = swzB(r, c*16, 128);
      const int ga = (n0 + r)*512 + kb + c*8;
      const int gb = (c0 + r)*512 + kb + c*8;
      *(uint4*)(ls + dst)         = *(const uint4*)(Ahi  + ga);
      *(uint4*)(ls + 16384 + dst) = *(const uint4*)(Bthi + gb);
      if constexpr (TERMS >= 3) {
        *(uint4*)(ls + 8192  + dst) = *(const uint4*)(Alo  + ga);
        *(uint4*)(ls + 24576 + dst) = *(const uint4*)(Btlo + gb);
      }
    }
    __syncthreads();
    #pragma unroll
    for (int ks = 0; ks < 2; ++ks) {
      const u32 co = ks*64 + lg*16;
      bf8_t ah[2], bh[2], al[2], bl[2];
      #pragma unroll
      for (int i=0;i<2;++i) {
        ah[i] = *(const bf8_t*)(ls +         swzB(wr*32 + i*16 + lr, co, 128));
        bh[i] = *(const bf8_t*)(ls + 16384 + swzB(wc*32 + i*16 + lr, co, 128));
        if constexpr (TERMS >= 3) {
          al[i] = *(const bf8_t*)(ls + 8192  + swzB(wr*32 + i*16 + lr, co, 128));
          bl[i] = *(const bf8_t*)(ls + 24576 + swzB(wc*32 + i*16 + lr, co, 128));
        }
      }
      #pragma unroll
      for (int i=0;i<2;++i)
        #pragma unroll
        for (int j=0;j<2;++j) {
          acc[i][j] = __builtin_amdgcn_mfma_f32_16x16x32_bf16(ah[i], bh[j], acc[i][j], 0,0,0);
          if constexpr (TERMS >= 3) {
            acc[i][j] = __builtin_amdgcn_mfma_f32_16x16x32_bf16(ah[i], bl[j], acc[i][j], 0,0,0);
            acc[i][j] = __builtin_amdgcn_mfma_f32_16x16x32_bf16(al[i], bh[j], acc[i][j], 0,0,0);
          }
        }
    }
  }
  #pragma unroll
  for (int i=0;i<2;++i)
    #pragma unroll
    for (int j=0;j<2;++j) {
      const int col = c0 + wc*32 + j*16 + lr;
      #pragma unroll
      for (int r=0;r<4;++r) {
        const int row = n0 + wr*32 + i*16 + lg*4 + r;
        float v = acc[i][j][r];
        if constexpr (EPI == EPI_GELU) {
          v += bias[col];
          outF[row*512 + col] = 0.5f * v * (1.0f + erff(v * 0.70710678118654752f));
        } else if constexpr (EPI == EPI_BF16) {
          outA[row*512 + col] = f2bf(v);
        } else if constexpr (EPI == EPI_VT) {
          outA[col*4096 + row] = f2bf(v);                 // V transposed [d][n]
        } else {
          outF[row*512 + col] = v + resid[row*512 + col]; // residual add
        }
      }
    }
}

// ---------------- fused attention v2 ----------------
// Swapped QK^T (A=K, B=Q): C[row=m][col=n]. Q frags in regs; K,V frags direct
// from global (L2-resident, XCD head-affinity). LDS only holds P [64 n][128 m].
// pass1: row sums l_n; pass2: p = exp*rinv, packed P via v_cvt_pk_bf16_f32, PV.
__global__ __launch_bounds__(256) void k_attn(
    const u16* __restrict__ qhi, const u16* __restrict__ khi,
    const u16* __restrict__ vt,  u16* __restrict__ ov, float* __restrict__ Apart)
{
  __shared__ __align__(16) char ls[16384];
  const int t = threadIdx.x, w = t >> 6, lane = t & 63;
  const int lr = lane & 15, lg = lane >> 4;
  const int bid = blockIdx.x;
  const int h = bid & 7, nb = bid >> 3;        // XCD affinity: one head per XCD
  const int n0 = nb * 64, qc0 = h * 64;
  const float cexp = 0.18033688011112042f;     // log2(e)/8

  // Q fragments (B-operand): lane holds Q[n0+b*16+lr][qc0+ks*32+lg*8+j]
  bf8_t qf[4][2];
  #pragma unroll
  for (int b=0;b<4;++b)
    #pragma unroll
    for (int ks=0;ks<2;++ks)
      qf[b][ks] = *(const bf8_t*)(qhi + (n0 + b*16 + lr)*512 + qc0 + ks*32 + lg*8);

  const u16* kbase = khi + (size_t)(w*32 + lr)*512 + qc0 + lg*8;
  const u16* vbase = vt + (size_t)(qc0 + w*16 + lr)*4096 + lg*8;

  // ---- pass 1: l_n ----
  float rs[4] = {0.f,0.f,0.f,0.f};
  for (int mt = 0; mt < 32; ++mt) {
    const u16* kb = kbase + (size_t)(mt*128)*512;
    f32x4 sacc[2][4];
    #pragma unroll
    for (int a=0;a<2;++a)
      #pragma unroll
      for (int b=0;b<4;++b) sacc[a][b] = f32x4{0.f,0.f,0.f,0.f};
    #pragma unroll
    for (int ks=0;ks<2;++ks){
      const bf8_t ka0 = *(const bf8_t*)(kb + ks*32);
      const bf8_t ka1 = *(const bf8_t*)(kb + 16*512 + ks*32);
      #pragma unroll
      for (int b=0;b<4;++b){
        sacc[0][b] = __builtin_amdgcn_mfma_f32_16x16x32_bf16(ka0, qf[b][ks], sacc[0][b], 0,0,0);
        sacc[1][b] = __builtin_amdgcn_mfma_f32_16x16x32_bf16(ka1, qf[b][ks], sacc[1][b], 0,0,0);
      }
    }
    #pragma unroll
    for (int a=0;a<2;++a)
      #pragma unroll
      for (int b=0;b<4;++b)
        #pragma unroll
        for (int r=0;r<4;++r)
          rs[b] += __builtin_amdgcn_exp2f(sacc[a][b][r] * cexp);
  }
  #pragma unroll
  for (int b=0;b<4;++b){ rs[b] += __shfl_xor(rs[b],16); rs[b] += __shfl_xor(rs[b],32); }
  {
    float* red = (float*)ls;            // [4][64]
    if (lg == 0){
      #pragma unroll
      for (int b=0;b<4;++b) red[w*64 + b*16 + lr] = rs[b];
    }
    __syncthreads();
    float* rinv = (float*)(ls + 1024);
    if (t < 64) rinv[t] = 1.0f / (red[t] + red[64+t] + red[128+t] + red[192+t]);
    __syncthreads();
  }
  float rv[4];
  #pragma unroll
  for (int b=0;b<4;++b) rv[b] = ((const float*)(ls + 1024))[b*16 + lr];

  // ---- pass 2 ----
  f32x4 oacc[4];
  #pragma unroll
  for (int i=0;i<4;++i) oacc[i] = f32x4{0.f,0.f,0.f,0.f};
  for (int mt = 0; mt < 32; ++mt) {
    const int m0 = mt * 128;
    const u16* kb = kbase + (size_t)m0*512;
    f32x4 sacc[2][4];
    #pragma unroll
    for (int a=0;a<2;++a)
      #pragma unroll
      for (int b=0;b<4;++b) sacc[a][b] = f32x4{0.f,0.f,0.f,0.f};
    #pragma unroll
    for (int ks=0;ks<2;++ks){
      const bf8_t ka0 = *(const bf8_t*)(kb + ks*32);
      const bf8_t ka1 = *(const bf8_t*)(kb + 16*512 + ks*32);
      #pragma unroll
      for (int b=0;b<4;++b){
        sacc[0][b] = __builtin_amdgcn_mfma_f32_16x16x32_bf16(ka0, qf[b][ks], sacc[0][b], 0,0,0);
        sacc[1][b] = __builtin_amdgcn_mfma_f32_16x16x32_bf16(ka1, qf[b][ks], sacc[1][b], 0,0,0);
      }
    }
    __syncthreads();              // previous iteration's PV reads of P are done
    float cs[2][4];
    #pragma unroll
    for (int a=0;a<2;++a){ cs[a][0]=0.f; cs[a][1]=0.f; cs[a][2]=0.f; cs[a][3]=0.f; }
    #pragma unroll
    for (int a=0;a<2;++a){
      const u32 mbyte = (w*32 + a*16 + lg*4)*2;
      #pragma unroll
      for (int b=0;b<4;++b){
        const float p0 = __builtin_amdgcn_exp2f(sacc[a][b][0]*cexp) * rv[b];
        const float p1 = __builtin_amdgcn_exp2f(sacc[a][b][1]*cexp) * rv[b];
        const float p2 = __builtin_amdgcn_exp2f(sacc[a][b][2]*cexp) * rv[b];
        const float p3 = __builtin_amdgcn_exp2f(sacc[a][b][3]*cexp) * rv[b];
        cs[a][0]+=p0; cs[a][1]+=p1; cs[a][2]+=p2; cs[a][3]+=p3;
        u32 u01, u23;
        asm("v_cvt_pk_bf16_f32 %0, %1, %2" : "=v"(u01) : "v"(p0), "v"(p1));
        asm("v_cvt_pk_bf16_f32 %0, %1, %2" : "=v"(u23) : "v"(p2), "v"(p3));
        const u32 base = swzB(b*16 + lr, mbyte, 256);
        *(u32*)(ls + base)     = u01;
        *(u32*)(ls + base + 4) = u23;
      }
    }
    #pragma unroll
    for (int a=0;a<2;++a)
      #pragma unroll
      for (int r=0;r<4;++r){
        float v = cs[a][r];
        v += __shfl_xor(v,1); v += __shfl_xor(v,2);
        v += __shfl_xor(v,4); v += __shfl_xor(v,8);
        cs[a][r] = v;
      }
    if (lr == 0){
      const int base = (h*64 + nb)*4096 + m0 + w*32;
      #pragma unroll
      for (int a=0;a<2;++a)
        #pragma unroll
        for (int r=0;r<4;++r)
          Apart[base + a*16 + lg*4 + r] = cs[a][r];
    }
    __syncthreads();              // P fully written
    #pragma unroll
    for (int ks2 = 0; ks2 < 4; ++ks2) {
      const bf8_t bv = *(const bf8_t*)(vbase + m0 + ks2*32);
      const u32 co = ks2*64 + lg*16;
      #pragma unroll
      for (int i=0;i<4;++i){
        const bf8_t ap = *(const bf8_t*)(ls + swzB(i*16 + lr, co, 256));
        oacc[i] = __builtin_amdgcn_mfma_f32_16x16x32_bf16(ap, bv, oacc[i], 0,0,0);
      }
    }
  }
  #pragma unroll
  for (int i=0;i<4;++i)
    #pragma unroll
    for (int r=0;r<4;++r){
      const int row = n0 + i*16 + lg*4 + r;
      const int col = qc0 + w*16 + lr;
      ov[row*512 + col] = f2bf(oacc[i][r]);
    }
}

// ---------------- A reduction (deterministic fp64) + exact stable-argsort top/bottom-K ----------------
__global__ void k_reduceA(const float* __restrict__ Apart, double* __restrict__ A64){
  const int m = blockIdx.x*256 + threadIdx.x;
  double s = 0.0;
  for (int b=0;b<512;++b) s += (double)Apart[b*4096 + m];
  A64[m] = s;
}

__global__ __launch_bounds__(256) void k_select(const double* __restrict__ A64, int* __restrict__ idx){
  __shared__ double Aw[4096];
  __shared__ double bv[256];
  __shared__ int    bi[256];
  const int t = threadIdx.x;
  for (int i=t;i<4096;i+=256) Aw[i] = A64[i];
  __syncthreads();
  for (int k=0;k<10;++k){                         // top-K: max, tie -> smaller index
    double best = -1e300; int bidx = 1<<30;
    for (int i=t;i<4096;i+=256){
      const double v = Aw[i];
      if (v > best){ best = v; bidx = i; }
    }
    bv[t]=best; bi[t]=bidx;
    __syncthreads();
    for (int s2=128;s2>0;s2>>=1){
      if (t < s2){
        const double v = bv[t+s2]; const int ii = bi[t+s2];
        if (v > bv[t] || (v == bv[t] && ii < bi[t])){ bv[t]=v; bi[t]=ii; }
      }
      __syncthreads();
    }
    if (t==0){ idx[k] = bi[0]; Aw[bi[0]] = -1e300; }
    __syncthreads();
  }
  for (int i=t;i<4096;i+=256) Aw[i] = A64[i];
  __syncthreads();
  for (int k=0;k<10;++k){                         // bottom-K from the end: min, tie -> larger index
    double best = 1e300; int bidx = -1;
    for (int i=t;i<4096;i+=256){
      const double v = Aw[i];
      if (v < best || (v == best && i > bidx)){ best = v; bidx = i; }
    }
    bv[t]=best; bi[t]=bidx;
    __syncthreads();
    for (int s2=128;s2>0;s2>>=1){
      if (t < s2){
        const double v = bv[t+s2]; const int ii = bi[t+s2];
        if (v < bv[t] || (v == bv[t] && ii > bi[t])){ bv[t]=v; bi[t]=ii; }
      }
      __syncthreads();
    }
    if (t==0){ idx[19-k] = bi[0]; Aw[bi[0]] = 1e300; }
    __syncthreads();
  }
}

// ---------------- feats = LN(x_res): mean over rows (partials), and selected rows ----------------
__global__ __launch_bounds__(256) void k_slide_part(const float* __restrict__ xres,
                                                    float* __restrict__ spart){
  __shared__ float acc[4][512];
  const int t = threadIdx.x, w = t >> 6, lane = t & 63;
  float la[8];
  #pragma unroll
  for (int i=0;i<8;++i) la[i]=0.f;
  for (int rr = 0; rr < 16; ++rr) {
    const int row = blockIdx.x*64 + w*16 + rr;
    const float* xr = xres + row*512;
    float v[8];
    f32x4 a  = *(const f32x4*)(xr + lane*8);
    f32x4 a2 = *(const f32x4*)(xr + lane*8 + 4);
    v[0]=a.x; v[1]=a.y; v[2]=a.z; v[3]=a.w; v[4]=a2.x; v[5]=a2.y; v[6]=a2.z; v[7]=a2.w;
    float s = v[0]+v[1]+v[2]+v[3]+v[4]+v[5]+v[6]+v[7];
    #pragma unroll
    for (int m=1;m<64;m<<=1) s += __shfl_xor(s, m);
    const float mean = s * (1.0f/512.0f);
    float q = 0.f;
    #pragma unroll
    for (int i=0;i<8;++i){ const float d = v[i]-mean; q += d*d; }
    #pragma unroll
    for (int m=1;m<64;m<<=1) q += __shfl_xor(q, m);
    const float rstd = 1.0f / sqrtf(q*(1.0f/512.0f) + 1e-5f);
    #pragma unroll
    for (int i=0;i<8;++i) la[i] += (v[i]-mean)*rstd;   // g,b applied at reduce (linear)
  }
  #pragma unroll
  for (int i=0;i<8;++i) acc[w][lane*8+i] = la[i];
  __syncthreads();
  for (int c = t; c < 512; c += 256)
    spart[blockIdx.x*512 + c] = acc[0][c]+acc[1][c]+acc[2][c]+acc[3][c];
}

__global__ void k_slide_reduce(const float* __restrict__ spart, const float* __restrict__ g,
                               const float* __restrict__ b, float* __restrict__ tok){
  const int c = blockIdx.x*256 + threadIdx.x;
  float s = 0.f;
  for (int bb=0;bb<64;++bb) s += spart[bb*512 + c];
  tok[c] = g[c]*(s*(1.0f/4096.0f)) + b[c];
}

__global__ void k_atte(const float* __restrict__ xres, const int* __restrict__ idx,
                       const float* __restrict__ g, const float* __restrict__ b,
                       float* __restrict__ atte){
  const int i = blockIdx.x, lane = threadIdx.x;   // 64 threads = 1 wave
  const int row = idx[i];
  const float* xr = xres + row*512;
  float v[8];
  f32x4 a  = *(const f32x4*)(xr + lane*8);
  f32x4 a2 = *(const f32x4*)(xr + lane*8 + 4);
  v[0]=a.x; v[1]=a.y; v[2]=a.z; v[3]=a.w; v[4]=a2.x; v[5]=a2.y; v[6]=a2.z; v[7]=a2.w;
  float s = v[0]+v[1]+v[2]+v[3]+v[4]+v[5]+v[6]+v[7];
  #pragma unroll
  for (int m=1;m<64;m<<=1) s += __shfl_xor(s, m);
  const float mean = s * (1.0f/512.0f);
  float q = 0.f;
  #pragma unroll
  for (int i2=0;i2<8;++i2){ const float d = v[i2]-mean; q += d*d; }
  #pragma unroll
  for (int m=1;m<64;m<<=1) q += __shfl_xor(q, m);
  const float rstd = 1.0f / sqrtf(q*(1.0f/512.0f) + 1e-5f);
  #pragma unroll
  for (int i2=0;i2<8;++i2){
    const int c = lane*8 + i2;
    atte[i*512 + c] = (v[i2]-mean)*rstd*g[c] + b[c];
  }
}

// ---------------- head stage 1: concat GEMV (Wfc2 [1024][512]) + elementwise fused parts ----------------
__global__ __launch_bounds__(256) void k_fused(
    const float* __restrict__ tokH, const float* __restrict__ tokI,
    const float* __restrict__ Wfc2, const float* __restrict__ bfc2,
    float* __restrict__ fused)
{
  __shared__ float part[8][32];
  const int t = threadIdx.x;
  const int jj = t & 31, rg = t >> 5;
  const int j = blockIdx.x*32 + jj;
  float s = 0.f;
  for (int r = rg; r < 1024; r += 8){
    const float xv = (r < 512) ? tokH[r] : tokI[r-512];
    s += xv * Wfc2[r*512 + j];
  }
  part[rg][jj] = s;
  __syncthreads();
  if (t < 32){
    const int jo = blockIdx.x*32 + t;
    float acc = bfc2[jo];
    #pragma unroll
    for (int g=0; g<8; ++g) acc += part[g][t];
    const float hv = tokH[jo], iv = tokI[jo];
    fused[jo]        = hv + iv;
    fused[512 + jo]  = hv * iv;
    fused[1024 + jo] = acc;
  }
}

// ---------------- head stage 2: g1 = gelu(fused @ Wc1 + bc1), Wc1 [1536][512] ----------------
__global__ __launch_bounds__(256) void k_g1(
    const float* __restrict__ fused, const float* __restrict__ Wc1,
    const float* __restrict__ bc1, float* __restrict__ g1)
{
  __shared__ float part[8][32];
  const int t = threadIdx.x;
  const int jj = t & 31, rg = t >> 5;
  const int j = blockIdx.x*32 + jj;
  float s = 0.f;
  for (int r = rg; r < 1536; r += 8)
    s += fused[r] * Wc1[r*512 + j];
  part[rg][jj] = s;
  __syncthreads();
  if (t < 32){
    const int jo = blockIdx.x*32 + t;
    float acc = bc1[jo];
    #pragma unroll
    for (int g=0; g<8; ++g) acc += part[g][t];
    g1[jo] = 0.5f*acc*(1.0f + erff(acc*0.70710678118654752f));
  }
}

// ---------------- head stage 3: Lm[20][20] cosine-sim matrix ----------------
__global__ __launch_bounds__(256) void k_lm(
    const float* __restrict__ atteH, const float* __restrict__ atteI,
    const float* __restrict__ lscale, float* __restrict__ Lm)
{
  __shared__ float ra[512];
  __shared__ float nAs;
  const int a = blockIdx.x, t = threadIdx.x, w = t >> 6, l = t & 63;
  for (int i=t;i<512;i+=256) ra[i] = atteH[a*512+i];
  __syncthreads();
  if (w == 0){
    float s = 0.f;
    #pragma unroll
    for (int k=0;k<8;++k){ const float v = ra[l + k*64]; s += v*v; }
    #pragma unroll
    for (int m=1;m<64;m<<=1) s += __shfl_xor(s, m);
    if (l == 0) nAs = s;
  }
  __syncthreads();
  const float scale = expf(lscale[0]);
  const float nA = sqrtf(nAs);
  for (int bi = 0; bi < 5; ++bi){
    const int b = w + bi*4;
    float dot = 0.f, nb = 0.f;
    #pragma unroll
    for (int k=0;k<8;++k){
      const float vb = atteI[b*512 + l + k*64];
      dot += ra[l + k*64]*vb;
      nb  += vb*vb;
    }
    #pragma unroll
    for (int m=1;m<64;m<<=1){ dot += __shfl_xor(dot,m); nb += __shfl_xor(nb,m); }
    if (l == 0) Lm[a*20 + b] = scale * dot / (nA * sqrtf(nb));
  }
}

// ---------------- head stage 4: classifier logits + contrastive loss ----------------
__global__ __launch_bounds__(256) void k_loss(
    const float* __restrict__ tokH, const float* __restrict__ tokI,
    const float* __restrict__ g1G, const float* __restrict__ LmG,
    const float* __restrict__ WheC, const float* __restrict__ bheC,
    const float* __restrict__ WihcC, const float* __restrict__ bihcC,
    const float* __restrict__ Wc2, const float* __restrict__ bc2,
    float* __restrict__ out)
{
  __shared__ float sH[512], sI[512], g1[512];
  __shared__ float Lm[20][20];
  __shared__ double terms[512];
  const int t = threadIdx.x, w = t >> 6, l = t & 63;
  for (int i=t;i<512;i+=256){ sH[i]=tokH[i]; sI[i]=tokI[i]; g1[i]=g1G[i]; }
  for (int i=t;i<400;i+=256) ((float*)Lm)[i] = LmG[i];
  __syncthreads();
  if (w < 3){
    const float* x  = (w==0)? sH   : (w==1)? sI    : g1;
    const float* W  = (w==0)? WheC : (w==1)? WihcC : Wc2;
    const float* bb = (w==0)? bheC : (w==1)? bihcC : bc2;
    const int c = l & 3, rg = l >> 2;
    float s = 0.f;
    for (int r = rg; r < 512; r += 16) s += x[r]*W[r*4+c];
    #pragma unroll
    for (int m=4;m<64;m<<=1) s += __shfl_xor(s, m);
    if (rg == 0) out[w*4 + c] = s + bb[c];
  }
  for (int e=t;e<512;e+=256){
    double res = 0.0;
    if (e < 400){
      const int r = e % 10, part = (e/10) % 2, i2 = (e/20) % 10, half = e/200;
      const int a = part ? (10 + r) : r;
      const int c0 = part ? (10 + i2) : i2;
      const int qb = part ? 0 : 10;
      auto Mget = [&](int aa, int bb)->double{
        return (double)(half ? Lm[bb][aa] : Lm[aa][bb]);
      };
      const double v0 = Mget(a, c0);
      double mx = v0;
      #pragma unroll
      for (int q=0;q<10;++q){ const double v = Mget(a, qb+q); if (v > mx) mx = v; }
      double se = exp(v0 - mx);
      #pragma unroll
      for (int q=0;q<10;++q) se += exp(Mget(a, qb+q) - mx);
      res = (log(se) + mx) - v0;
    }
    terms[e] = res;
  }
  __syncthreads();
  for (int s2=256;s2>0;s2>>=1){
    if (t < s2) terms[t] += terms[t+s2];
    __syncthreads();
  }
  if (t == 0) {
    const float cl = (float)(terms[0] / 400.0);
    out[12]=cl; out[13]=cl; out[14]=cl; out[15]=cl;
  }
}

// ---------------- launcher ----------------
extern "C" void kernel_launch(void* const* d_in, const int* in_sizes, int n_in,
                              void* d_out, int out_size, void* d_ws, size_t ws_size,
                              hipStream_t stream)
{
  (void)in_sizes; (void)n_in; (void)out_size; (void)ws_size;
  auto F = [&](int i){ return (const float*)d_in[i]; };
  char* ws = (char*)d_ws;
  size_t off = 0;
  auto alloc = [&](size_t sz)->void*{ void* p = ws + off; off += (sz + 255) & ~((size_t)255); return p; };

  float* xg   = (float*)alloc((size_t)4096*512*4);   // gelu(fc) output
  float* AX   = (float*)alloc((size_t)512*4096*4);   // Apart, then x_res
  u16*   shi  = (u16*)alloc((size_t)4096*512*2);     // x-split hi, later h-split hi
  u16*   slo  = (u16*)alloc((size_t)4096*512*2);     // x-split lo, later h-split lo
  u16*   qh   = (u16*)alloc((size_t)4096*512*2);     // Q bf16
  u16*   kh   = (u16*)alloc((size_t)4096*512*2);     // K bf16
  u16*   vT   = (u16*)alloc((size_t)512*4096*2);     // V transposed [d][n]
  u16*   ov   = (u16*)alloc((size_t)4096*512*2);     // attn output (pre-Wo), bf16
  u16*   wb   = (u16*)alloc((size_t)5*2*262144*2);   // 5 weights x (hi,lo) transposed
  double* A64 = (double*)alloc((size_t)4096*8);
  int*   idxH = (int*)alloc(80);
  int*   idxI = (int*)alloc(80);
  float* spart= (float*)alloc((size_t)64*512*4);
  float* tokH = (float*)alloc(512*4);
  float* tokI = (float*)alloc(512*4);
  float* atteH= (float*)alloc((size_t)20*512*4);
  float* atteI= (float*)alloc((size_t)20*512*4);
  float* fusedW = (float*)alloc(1536*4);
  float* g1W    = (float*)alloc(512*4);
  float* LmW    = (float*)alloc(400*4);

  for (int br = 0; br < 2; ++br) {
    const float* x   = F(br?1:0);
    const float* Wfc = F(br?4:2);
    const float* bfc = F(br?5:3);
    const float* lng = F(br?12:6);
    const float* lnb = F(br?13:7);
    const float* Wq  = F(br?14:8);
    const float* Wk  = F(br?15:9);
    const float* Wv  = F(br?16:10);
    const float* Wo  = F(br?17:11);
    int*   idx = br ? idxI : idxH;
    float* tok = br ? tokI : tokH;
    float* att = br ? atteI : atteH;
    u16* WHI0 = wb;              u16* WLO0 = wb + 262144;
    u16* WHI1 = wb + 524288;     u16* WLO1 = wb + 524288 + 262144;
    u16* WHI2 = wb + 1048576;    u16* WLO2 = wb + 1048576 + 262144;
    u16* WHI3 = wb + 1572864;
    u16* WHI4 = wb + 2097152;

    k_split_act<<<8192,256,0,stream>>>(x, shi, slo, 4096*512);
    k_split_w5<<<dim3(1024,5),256,0,stream>>>(Wfc, Wq, Wk, Wv, Wo, wb);
    k_gemm512<3,EPI_GELU><<<dim3(64,8),256,0,stream>>>(shi,slo,WHI0,WLO0,bfc,nullptr,xg,nullptr);
    k_ln_split<<<1024,256,0,stream>>>(xg,lng,lnb,shi,slo);
    k_gemm512<3,EPI_BF16><<<dim3(64,8),256,0,stream>>>(shi,slo,WHI1,WLO1,nullptr,nullptr,nullptr,qh);
    k_gemm512<3,EPI_BF16><<<dim3(64,8),256,0,stream>>>(shi,slo,WHI2,WLO2,nullptr,nullptr,nullptr,kh);
    k_gemm512<1,EPI_VT><<<dim3(64,8),256,0,stream>>>(shi,nullptr,WHI3,nullptr,nullptr,nullptr,nullptr,vT);
    k_attn<<<512,256,0,stream>>>(qh,kh,vT,ov,AX);
    k_reduceA<<<16,256,0,stream>>>(AX, A64);
    k_select<<<1,256,0,stream>>>(A64, idx);
    k_gemm512<1,EPI_RES><<<dim3(64,8),256,0,stream>>>(ov,nullptr,WHI4,nullptr,nullptr,xg,AX,nullptr);
    k_slide_part<<<64,256,0,stream>>>(AX, spart);
    k_slide_reduce<<<2,256,0,stream>>>(spart, F(18), F(19), tok);
    k_atte<<<20,64,0,stream>>>(AX, idx, F(18), F(19), att);
  }
  k_fused<<<16,256,0,stream>>>(tokH, tokI, F(24), F(25), fusedW);
  k_g1<<<16,256,0,stream>>>(fusedW, F(26), F(27), g1W);
  k_lm<<<20,256,0,stream>>>(atteH, atteI, F(30), LmW);
  k_loss<<<1,256,0,stream>>>(tokH, tokI, g1W, LmW,
                             F(20), F(21), F(22), F(23), F(28), F(29),
                             (float*)d_out);
}